// Round 8
// baseline (734.177 us; speedup 1.0000x reference)
//
#include <hip/hip_runtime.h>
#include <hip/hip_bf16.h>

#define NEG_SLOPE 0.2f

#define EDOT(P0,P1,P2,P3) (P0.x*wreg[0]+P0.y*wreg[1]+P0.z*wreg[2]+P0.w*wreg[3]+ \
  P1.x*wreg[4]+P1.y*wreg[5]+P1.z*wreg[6]+P1.w*wreg[7]+ \
  P2.x*wreg[8]+P2.y*wreg[9]+P2.z*wreg[10]+P2.w*wreg[11]+ \
  P3.x*wreg[12]+P3.y*wreg[13]+P3.z*wreg[14]+P3.w*wreg[15])

// ------------------------------------------------------------ CSR build
__global__ void zero_int_k(int* __restrict__ p, int n) {
  int i = blockIdx.x * blockDim.x + threadIdx.x;
  if (i < n) p[i] = 0;
}

__global__ void deg_count_k(const int* __restrict__ dstA, int* __restrict__ deg, int E) {
  int e = blockIdx.x * blockDim.x + threadIdx.x;
  if (e < E) atomicAdd(&deg[dstA[e]], 1);
}

// exclusive scan, 3 phases (N <= 512*256)
__global__ void scan1_k(const int* __restrict__ deg, int* __restrict__ rowptr,
                        int* __restrict__ aux, int N) {
  __shared__ int sh[256];
  int t = threadIdx.x, i = blockIdx.x * 256 + t;
  int v = (i < N) ? deg[i] : 0;
  sh[t] = v; __syncthreads();
  for (int off = 1; off < 256; off <<= 1) {
    int x = (t >= off) ? sh[t - off] : 0;
    __syncthreads();
    sh[t] += x;
    __syncthreads();
  }
  if (i < N) rowptr[i] = sh[t] - v;
  if (t == 255) aux[blockIdx.x] = sh[255];
}

__global__ void scan2_k(int* __restrict__ aux, int naux) {
  __shared__ int sh[512];
  int t = threadIdx.x;
  int v = (t < naux) ? aux[t] : 0;
  sh[t] = v; __syncthreads();
  for (int off = 1; off < 512; off <<= 1) {
    int x = (t >= off) ? sh[t - off] : 0;
    __syncthreads();
    sh[t] += x;
    __syncthreads();
  }
  if (t < naux) aux[t] = sh[t] - v;
}

__global__ void scan3_k(int* __restrict__ rowptr, int* __restrict__ cursor,
                        const int* __restrict__ aux, int N, int E) {
  int i = blockIdx.x * blockDim.x + threadIdx.x;
  if (i < N) {
    int r = rowptr[i] + aux[i >> 8];
    rowptr[i] = r;
    cursor[i] = r;
  } else if (i == N) {
    rowptr[N] = E;
  }
}

__global__ void scatter_k(const int* __restrict__ srcA, const int* __restrict__ dstA,
                          int* __restrict__ cursor, int* __restrict__ csr_src,
                          int* __restrict__ csr_eid, int E) {
  int e = blockIdx.x * blockDim.x + threadIdx.x;
  if (e >= E) return;
  int pos = atomicAdd(&cursor[dstA[e]], 1);
  csr_src[pos] = srcA[e];
  csr_eid[pos] = e;
}

// ------------------------------------------------- layer1 node transform (128 -> 64|64)
__global__ __launch_bounds__(256) void transform1_k(
    const float* __restrict__ x, const float* __restrict__ wl, const float* __restrict__ wr,
    float* __restrict__ xl, float* __restrict__ xr, int N) {
  __shared__ float wS[128 * 128];
  __shared__ float xs[32 * 128];
  int t = threadIdx.x;
  for (int i = t; i < 128 * 64; i += 256) {
    int k = i >> 6, j = i & 63;
    wS[k * 128 + j]      = wl[i];
    wS[k * 128 + 64 + j] = wr[i];
  }
  __syncthreads();
  int tc = t & 31;
  int tr = t >> 5;
  int ntiles = (N + 31) >> 5;
  for (int tile = blockIdx.x; tile < ntiles; tile += gridDim.x) {
    int base = tile << 5;
    const float4* x4 = (const float4*)x;
    float4* xs4 = (float4*)xs;
    for (int i = t; i < 1024; i += 256) {
      int node = base + (i >> 5);
      float4 v = {0.f, 0.f, 0.f, 0.f};
      if (node < N) v = x4[(size_t)node * 32 + (i & 31)];
      xs4[i] = v;
    }
    __syncthreads();
    float4 acc0 = {0,0,0,0}, acc1 = {0,0,0,0}, acc2 = {0,0,0,0}, acc3 = {0,0,0,0};
    const float* xrow = &xs[tr * 4 * 128];
#pragma unroll 4
    for (int k = 0; k < 128; ++k) {
      float4 w4 = *(const float4*)&wS[k * 128 + tc * 4];
      float x0 = xrow[k], x1 = xrow[128 + k], x2 = xrow[256 + k], x3 = xrow[384 + k];
      acc0.x += x0 * w4.x; acc0.y += x0 * w4.y; acc0.z += x0 * w4.z; acc0.w += x0 * w4.w;
      acc1.x += x1 * w4.x; acc1.y += x1 * w4.y; acc1.z += x1 * w4.z; acc1.w += x1 * w4.w;
      acc2.x += x2 * w4.x; acc2.y += x2 * w4.y; acc2.z += x2 * w4.z; acc2.w += x2 * w4.w;
      acc3.x += x3 * w4.x; acc3.y += x3 * w4.y; acc3.z += x3 * w4.z; acc3.w += x3 * w4.w;
    }
    float* dp = (tc < 16) ? xl : xr;
    int j4 = (tc & 15) * 4;
    int nb = base + tr * 4;
    if (nb + 0 < N) *(float4*)&dp[(size_t)(nb + 0) * 64 + j4] = acc0;
    if (nb + 1 < N) *(float4*)&dp[(size_t)(nb + 1) * 64 + j4] = acc1;
    if (nb + 2 < N) *(float4*)&dp[(size_t)(nb + 2) * 64 + j4] = acc2;
    if (nb + 3 < N) *(float4*)&dp[(size_t)(nb + 3) * 64 + j4] = acc3;
    __syncthreads();
  }
}

// ------------------------------------------------- layer2 node transform (64 -> 32|32)
__global__ __launch_bounds__(256) void transform2_k(
    const float* __restrict__ h, const float* __restrict__ wl, const float* __restrict__ wr,
    float* __restrict__ xl, float* __restrict__ xr, int N) {
  __shared__ float wS[64 * 64];
  __shared__ float xs[64 * 64];
  int t = threadIdx.x;
  for (int i = t; i < 64 * 32; i += 256) {
    int k = i >> 5, j = i & 31;
    wS[k * 64 + j]      = wl[i];
    wS[k * 64 + 32 + j] = wr[i];
  }
  __syncthreads();
  int tc = t & 15;
  int tr = t >> 4;
  int ntiles = (N + 63) >> 6;
  for (int tile = blockIdx.x; tile < ntiles; tile += gridDim.x) {
    int base = tile << 6;
    const float4* h4 = (const float4*)h;
    float4* xs4 = (float4*)xs;
    for (int i = t; i < 1024; i += 256) {
      int node = base + (i >> 4);
      float4 v = {0.f, 0.f, 0.f, 0.f};
      if (node < N) v = h4[(size_t)node * 16 + (i & 15)];
      xs4[i] = v;
    }
    __syncthreads();
    float4 acc0 = {0,0,0,0}, acc1 = {0,0,0,0}, acc2 = {0,0,0,0}, acc3 = {0,0,0,0};
    const float* xrow = &xs[tr * 4 * 64];
#pragma unroll 4
    for (int k = 0; k < 64; ++k) {
      float4 w4 = *(const float4*)&wS[k * 64 + tc * 4];
      float x0 = xrow[k], x1 = xrow[64 + k], x2 = xrow[128 + k], x3 = xrow[192 + k];
      acc0.x += x0 * w4.x; acc0.y += x0 * w4.y; acc0.z += x0 * w4.z; acc0.w += x0 * w4.w;
      acc1.x += x1 * w4.x; acc1.y += x1 * w4.y; acc1.z += x1 * w4.z; acc1.w += x1 * w4.w;
      acc2.x += x2 * w4.x; acc2.y += x2 * w4.y; acc2.z += x2 * w4.z; acc2.w += x2 * w4.w;
      acc3.x += x3 * w4.x; acc3.y += x3 * w4.y; acc3.z += x3 * w4.z; acc3.w += x3 * w4.w;
    }
    float* dp = (tc < 8) ? xl : xr;
    int j4 = (tc & 7) * 4;
    int nb = base + tr * 4;
    if (nb + 0 < N) *(float4*)&dp[(size_t)(nb + 0) * 32 + j4] = acc0;
    if (nb + 1 < N) *(float4*)&dp[(size_t)(nb + 1) * 32 + j4] = acc1;
    if (nb + 2 < N) *(float4*)&dp[(size_t)(nb + 2) * 32 + j4] = acc2;
    if (nb + 3 < N) *(float4*)&dp[(size_t)(nb + 3) * 32 + j4] = acc3;
    __syncthreads();
  }
}

// ------------------------------------------------- GAT layer1: one wave per node (pull)
// 4 edges per iteration: batched loads -> batched dots -> 4 interleaved
// butterfly chains -> 4 exps; tail handled by clamp+mask (branch-free).
__global__ __launch_bounds__(256) void gat1_k(
    const int* __restrict__ rowptr, const int* __restrict__ csr_src,
    const int* __restrict__ csr_eid, const float* __restrict__ ea,
    const float* __restrict__ we, const float* __restrict__ att,
    const float* __restrict__ b, const float* __restrict__ xl,
    const float* __restrict__ xr, float* __restrict__ h, int N) {
  int t = threadIdx.x;
  int lane = t & 63;
  float wreg[16];
#pragma unroll
  for (int k = 0; k < 16; ++k) wreg[k] = we[k * 64 + lane];
  float att_r = att[lane];
  float b_r = b[lane];
  int wid = (blockIdx.x * blockDim.x + t) >> 6;
  int nwaves = (gridDim.x * blockDim.x) >> 6;
  for (int n = wid; n < N; n += nwaves) {
    float xr_v = xr[(size_t)n * 64 + lane];
    float xl_s = xl[(size_t)n * 64 + lane];
    float num = 0.f, den = 0.f, efsum = 0.f;
    int rs = rowptr[n], re = rowptr[n + 1];
    for (int base = rs; base < re; base += 64) {
      int cnt = min(64, re - base);
      int s_l = 0, e_l = 0;
      if (lane < cnt) { s_l = csr_src[base + lane]; e_l = csr_eid[base + lane]; }
      for (int i = 0; i < cnt; i += 4) {
        int j1 = min(i + 1, cnt - 1), j2 = min(i + 2, cnt - 1), j3 = min(i + 3, cnt - 1);
        int sa = __shfl(s_l, i),  sb = __shfl(s_l, j1);
        int sc_ = __shfl(s_l, j2), sd = __shfl(s_l, j3);
        int ia = __shfl(e_l, i),  ib = __shfl(e_l, j1);
        int ic = __shfl(e_l, j2), id = __shfl(e_l, j3);
        float xa = xl[(size_t)sa * 64 + lane];
        float xb = xl[(size_t)sb * 64 + lane];
        float xc = xl[(size_t)sc_ * 64 + lane];
        float xd = xl[(size_t)sd * 64 + lane];
        const float4* pa = (const float4*)(ea + (size_t)ia * 16);
        const float4* pb = (const float4*)(ea + (size_t)ib * 16);
        const float4* pc = (const float4*)(ea + (size_t)ic * 16);
        const float4* pd = (const float4*)(ea + (size_t)id * 16);
        float4 A0 = pa[0], A1 = pa[1], A2 = pa[2], A3 = pa[3];
        float4 B0 = pb[0], B1 = pb[1], B2 = pb[2], B3 = pb[3];
        float4 C0 = pc[0], C1 = pc[1], C2 = pc[2], C3 = pc[3];
        float4 D0 = pd[0], D1 = pd[1], D2 = pd[2], D3 = pd[3];
        float fa = EDOT(A0, A1, A2, A3);
        float fb = EDOT(B0, B1, B2, B3);
        float fc = EDOT(C0, C1, C2, C3);
        float fd = EDOT(D0, D1, D2, D3);
        float ma = xa + xr_v + fa; ma = (ma > 0.f) ? ma : NEG_SLOPE * ma;
        float mb = xb + xr_v + fb; mb = (mb > 0.f) ? mb : NEG_SLOPE * mb;
        float mc = xc + xr_v + fc; mc = (mc > 0.f) ? mc : NEG_SLOPE * mc;
        float md = xd + xr_v + fd; md = (md > 0.f) ? md : NEG_SLOPE * md;
        float ta = ma * att_r, tb = mb * att_r, tc2 = mc * att_r, td = md * att_r;
#pragma unroll
        for (int off = 1; off < 32; off <<= 1) {
          ta  += __shfl_xor(ta, off);
          tb  += __shfl_xor(tb, off);
          tc2 += __shfl_xor(tc2, off);
          td  += __shfl_xor(td, off);
        }
        float ga = __expf(ta), gb = __expf(tb), gc = __expf(tc2), gd = __expf(td);
        float kb = (i + 1 < cnt) ? 1.f : 0.f;
        float kc = (i + 2 < cnt) ? 1.f : 0.f;
        float kd = (i + 3 < cnt) ? 1.f : 0.f;
        num += ga * xa + kb * gb * xb + kc * gc * xc + kd * gd * xd;
        den += ga + kb * gb + kc * gc + kd * gd;
        efsum += fa + kb * fb + kc * fc + kd * fd;
      }
    }
    // self loop: ef_self = mean(ea@we) = efsum/deg
    int deg = re - rs;
    float ef_self = efsum / fmaxf((float)deg, 1.f);
    float mm = xl_s + xr_v + ef_self;
    mm = (mm > 0.f) ? mm : NEG_SLOPE * mm;
    float s2 = mm * att_r;
#pragma unroll
    for (int off = 1; off < 32; off <<= 1) s2 += __shfl_xor(s2, off);
    float e2 = __expf(s2);
    num += e2 * xl_s;
    den += e2;
    h[(size_t)n * 64 + lane] = fmaxf(num / fmaxf(den, 1e-16f) + b_r, 0.f);
  }
}

// ------------------------------------------------- GAT layer2: half-wave per node
__global__ __launch_bounds__(256) void gat2_k(
    const int* __restrict__ rowptr, const int* __restrict__ csr_src,
    const int* __restrict__ csr_eid, const float* __restrict__ ea,
    const float* __restrict__ we, const float* __restrict__ att,
    const float* __restrict__ b, const float* __restrict__ xl,
    const float* __restrict__ xr, float* __restrict__ h, int N) {
  int t = threadIdx.x;
  int lane = t & 63;
  int c = lane & 31;
  int half = lane >> 5;
  int hbase = lane & 32;
  float wreg[16];
#pragma unroll
  for (int k = 0; k < 16; ++k) wreg[k] = we[k * 32 + c];
  float att_r = att[c];
  float b_r = b[c];
  int wid = (blockIdx.x * blockDim.x + t) >> 6;
  int nwaves = (gridDim.x * blockDim.x) >> 6;
  for (int np = wid; np * 2 < N; np += nwaves) {
    int n = np * 2 + half;
    if (n >= N) continue;
    float xr_v = xr[(size_t)n * 32 + c];
    float xl_s = xl[(size_t)n * 32 + c];
    float num = 0.f, den = 0.f, efsum = 0.f;
    int rs = rowptr[n], re = rowptr[n + 1];
    for (int base = rs; base < re; base += 32) {
      int cnt = min(32, re - base);
      int s_l = 0, e_l = 0;
      if (c < cnt) { s_l = csr_src[base + c]; e_l = csr_eid[base + c]; }
      for (int i = 0; i < cnt; i += 4) {
        int j1 = min(i + 1, cnt - 1), j2 = min(i + 2, cnt - 1), j3 = min(i + 3, cnt - 1);
        int sa = __shfl(s_l, hbase + i),  sb = __shfl(s_l, hbase + j1);
        int sc_ = __shfl(s_l, hbase + j2), sd = __shfl(s_l, hbase + j3);
        int ia = __shfl(e_l, hbase + i),  ib = __shfl(e_l, hbase + j1);
        int ic = __shfl(e_l, hbase + j2), id = __shfl(e_l, hbase + j3);
        float xa = xl[(size_t)sa * 32 + c];
        float xb = xl[(size_t)sb * 32 + c];
        float xc = xl[(size_t)sc_ * 32 + c];
        float xd = xl[(size_t)sd * 32 + c];
        const float4* pa = (const float4*)(ea + (size_t)ia * 16);
        const float4* pb = (const float4*)(ea + (size_t)ib * 16);
        const float4* pc = (const float4*)(ea + (size_t)ic * 16);
        const float4* pd = (const float4*)(ea + (size_t)id * 16);
        float4 A0 = pa[0], A1 = pa[1], A2 = pa[2], A3 = pa[3];
        float4 B0 = pb[0], B1 = pb[1], B2 = pb[2], B3 = pb[3];
        float4 C0 = pc[0], C1 = pc[1], C2 = pc[2], C3 = pc[3];
        float4 D0 = pd[0], D1 = pd[1], D2 = pd[2], D3 = pd[3];
        float fa = EDOT(A0, A1, A2, A3);
        float fb = EDOT(B0, B1, B2, B3);
        float fc = EDOT(C0, C1, C2, C3);
        float fd = EDOT(D0, D1, D2, D3);
        float ma = xa + xr_v + fa; ma = (ma > 0.f) ? ma : NEG_SLOPE * ma;
        float mb = xb + xr_v + fb; mb = (mb > 0.f) ? mb : NEG_SLOPE * mb;
        float mc = xc + xr_v + fc; mc = (mc > 0.f) ? mc : NEG_SLOPE * mc;
        float md = xd + xr_v + fd; md = (md > 0.f) ? md : NEG_SLOPE * md;
        float ta = ma * att_r, tb = mb * att_r, tc2 = mc * att_r, td = md * att_r;
#pragma unroll
        for (int off = 1; off < 32; off <<= 1) {
          ta  += __shfl_xor(ta, off);
          tb  += __shfl_xor(tb, off);
          tc2 += __shfl_xor(tc2, off);
          td  += __shfl_xor(td, off);
        }
        float ga = __expf(ta), gb = __expf(tb), gc = __expf(tc2), gd = __expf(td);
        float kb = (i + 1 < cnt) ? 1.f : 0.f;
        float kc = (i + 2 < cnt) ? 1.f : 0.f;
        float kd = (i + 3 < cnt) ? 1.f : 0.f;
        num += ga * xa + kb * gb * xb + kc * gc * xc + kd * gd * xd;
        den += ga + kb * gb + kc * gc + kd * gd;
        efsum += fa + kb * fb + kc * fc + kd * fd;
      }
    }
    int deg = re - rs;
    float ef_self = efsum / fmaxf((float)deg, 1.f);
    float mm = xl_s + xr_v + ef_self;
    mm = (mm > 0.f) ? mm : NEG_SLOPE * mm;
    float s2 = mm * att_r;
#pragma unroll
    for (int off = 1; off < 32; off <<= 1) s2 += __shfl_xor(s2, off);
    float e2 = __expf(s2);
    num += e2 * xl_s;
    den += e2;
    h[(size_t)n * 32 + c] = fmaxf(num / fmaxf(den, 1e-16f) + b_r, 0.f);
  }
}

// ------------------------------------------------- fused mean-pool + fc
__global__ __launch_bounds__(256) void pool_fc_k(
    const float* __restrict__ h, const int* __restrict__ batch,
    const float* __restrict__ wfc, const float* __restrict__ bfc,
    float* __restrict__ out, int N) {
  int g = blockIdx.x;
  __shared__ int srange[2];
  __shared__ float part[8][32];
  int t = threadIdx.x;
  if (t < 2) {
    int key = g + t;
    int lo = 0, hi = N;
    while (lo < hi) { int mid = (lo + hi) >> 1; if (batch[mid] < key) lo = mid + 1; else hi = mid; }
    srange[t] = lo;
  }
  __syncthreads();
  int rs = srange[0], re = srange[1];
  int c = t & 31, sub = t >> 5;
  float acc = 0.f;
  for (int n = rs + sub; n < re; n += 8) acc += h[(size_t)n * 32 + c];
  part[sub][c] = acc;
  __syncthreads();
  if (sub == 0) {
    float s = part[0][c];
#pragma unroll
    for (int i = 1; i < 8; ++i) s += part[i][c];
    part[0][c] = s / fmaxf((float)(re - rs), 1.f);
  }
  __syncthreads();
  if (sub == 0) {
    float a = 0.f;
#pragma unroll
    for (int k = 0; k < 32; ++k) a += part[0][k] * wfc[k * 32 + c];
    out[g * 32 + c] = a + bfc[c];
  }
}

// ----------------------------------------------------------------- launcher
extern "C" void kernel_launch(void* const* d_in, const int* in_sizes, int n_in,
                              void* d_out, int out_size, void* d_ws, size_t ws_size,
                              hipStream_t stream) {
  const float* x   = (const float*)d_in[0];
  const int*   ei  = (const int*)d_in[1];
  const float* ea  = (const float*)d_in[2];
  const int*   bat = (const int*)d_in[3];
  const float* wl1 = (const float*)d_in[4];
  const float* wr1 = (const float*)d_in[5];
  const float* we1 = (const float*)d_in[6];
  const float* at1 = (const float*)d_in[7];
  const float* b1  = (const float*)d_in[8];
  const float* wl2 = (const float*)d_in[9];
  const float* wr2 = (const float*)d_in[10];
  const float* we2 = (const float*)d_in[11];
  const float* at2 = (const float*)d_in[12];
  const float* b2  = (const float*)d_in[13];
  const float* wfc = (const float*)d_in[14];
  const float* bfc = (const float*)d_in[15];

  const int N = in_sizes[0] / 128;
  const int E = in_sizes[1] / 2;
  const int G = 256;
  const int* srcA = ei;
  const int* dstA = ei + E;

  // ---- workspace layout ----
  int* deg      = (int*)d_ws;                  // N
  int* rowptr   = deg + N;                     // N+1
  int* cursor   = rowptr + (N + 1);            // N
  int* aux      = cursor + N;                  // 512
  int* csr_src  = aux + 512;                   // E
  int* csr_eid  = csr_src + E;                 // E
  float* xl1    = (float*)(csr_eid + E);       // N*64
  float* xr1    = xl1 + (size_t)N * 64;        // N*64
  float* h1     = xr1;                         // in-place over xr1
  float* xl2    = xl1;                         // N*32 (xl1 dead after gat1)
  float* xr2    = xl1 + (size_t)N * 32;        // N*32
  float* h2     = xr2;                         // in-place over xr2

  const int naux = (N + 255) / 256;

  // ---- CSR build ----
  zero_int_k<<<(N + 255) / 256, 256, 0, stream>>>(deg, N);
  deg_count_k<<<(E + 255) / 256, 256, 0, stream>>>(dstA, deg, E);
  scan1_k<<<naux, 256, 0, stream>>>(deg, rowptr, aux, N);
  scan2_k<<<1, 512, 0, stream>>>(aux, naux);
  scan3_k<<<(N + 256) / 256, 256, 0, stream>>>(rowptr, cursor, aux, N, E);
  scatter_k<<<(E + 255) / 256, 256, 0, stream>>>(srcA, dstA, cursor, csr_src, csr_eid, E);

  // ---- layer 1 ----
  transform1_k<<<2048, 256, 0, stream>>>(x, wl1, wr1, xl1, xr1, N);
  gat1_k<<<8192, 256, 0, stream>>>(rowptr, csr_src, csr_eid, ea, we1, at1, b1,
                                   xl1, xr1, h1, N);

  // ---- layer 2 ----
  transform2_k<<<1024, 256, 0, stream>>>(h1, wl2, wr2, xl2, xr2, N);
  gat2_k<<<8192, 256, 0, stream>>>(rowptr, csr_src, csr_eid, ea, we2, at2, b2,
                                   xl2, xr2, h2, N);

  // ---- fused pool + fc ----
  pool_fc_k<<<G, 256, 0, stream>>>(h2, bat, wfc, bfc, (float*)d_out, N);
}

// Round 9
// 607.268 us; speedup vs baseline: 1.2090x; 1.2090x over previous
//
#include <hip/hip_runtime.h>
#include <hip/hip_bf16.h>
#include <hip/hip_fp16.h>

#define NEG_SLOPE 0.2f

// ------------------------------------------------------------ CSR build
__global__ void deg_count_k(const int* __restrict__ dstA, int* __restrict__ deg, int E) {
  int e = blockIdx.x * blockDim.x + threadIdx.x;
  if (e < E) atomicAdd(&deg[dstA[e]], 1);
}

// exclusive scan, 3 phases (N <= 512*256)
__global__ void scan1_k(const int* __restrict__ deg, int* __restrict__ rowptr,
                        int* __restrict__ aux, int N) {
  __shared__ int sh[256];
  int t = threadIdx.x, i = blockIdx.x * 256 + t;
  int v = (i < N) ? deg[i] : 0;
  sh[t] = v; __syncthreads();
  for (int off = 1; off < 256; off <<= 1) {
    int x = (t >= off) ? sh[t - off] : 0;
    __syncthreads();
    sh[t] += x;
    __syncthreads();
  }
  if (i < N) rowptr[i] = sh[t] - v;
  if (t == 255) aux[blockIdx.x] = sh[255];
}

__global__ void scan2_k(int* __restrict__ aux, int naux) {
  __shared__ int sh[512];
  int t = threadIdx.x;
  int v = (t < naux) ? aux[t] : 0;
  sh[t] = v; __syncthreads();
  for (int off = 1; off < 512; off <<= 1) {
    int x = (t >= off) ? sh[t - off] : 0;
    __syncthreads();
    sh[t] += x;
    __syncthreads();
  }
  if (t < naux) aux[t] = sh[t] - v;
}

__global__ void scan3_k(int* __restrict__ rowptr, int* __restrict__ cursor,
                        const int* __restrict__ aux, int N, int E) {
  int i = blockIdx.x * blockDim.x + threadIdx.x;
  if (i < N) {
    int r = rowptr[i] + aux[i >> 8];
    rowptr[i] = r;
    cursor[i] = r;
  } else if (i == N) {
    rowptr[N] = E;
  }
}

// scatter: builds csr_src AND permuted fp16 edge-attrs (CSR order, 32B/edge)
__global__ void scatter_k(const int* __restrict__ srcA, const int* __restrict__ dstA,
                          const float* __restrict__ ea, int* __restrict__ cursor,
                          int* __restrict__ csr_src, uint4* __restrict__ ea_h, int E) {
  int e = blockIdx.x * blockDim.x + threadIdx.x;
  if (e >= E) return;
  int pos = atomicAdd(&cursor[dstA[e]], 1);
  csr_src[pos] = srcA[e];
  const float* p = ea + (size_t)e * 16;
  union { __half2 h2[8]; uint4 u[2]; } cv;
#pragma unroll
  for (int k = 0; k < 8; ++k) cv.h2[k] = __floats2half2_rn(p[2 * k], p[2 * k + 1]);
  uint4* d = ea_h + (size_t)pos * 2;
  d[0] = cv.u[0];
  d[1] = cv.u[1];
}

// ------------------------------------------------- layer1 node transform (128 -> 64|64)
__global__ __launch_bounds__(256) void transform1_k(
    const float* __restrict__ x, const float* __restrict__ wl, const float* __restrict__ wr,
    float* __restrict__ xl, float* __restrict__ xr, int N) {
  __shared__ float wS[128 * 128];
  __shared__ float xs[32 * 128];
  int t = threadIdx.x;
  for (int i = t; i < 128 * 64; i += 256) {
    int k = i >> 6, j = i & 63;
    wS[k * 128 + j]      = wl[i];
    wS[k * 128 + 64 + j] = wr[i];
  }
  __syncthreads();
  int tc = t & 31;
  int tr = t >> 5;
  int ntiles = (N + 31) >> 5;
  for (int tile = blockIdx.x; tile < ntiles; tile += gridDim.x) {
    int base = tile << 5;
    const float4* x4 = (const float4*)x;
    float4* xs4 = (float4*)xs;
    for (int i = t; i < 1024; i += 256) {
      int node = base + (i >> 5);
      float4 v = {0.f, 0.f, 0.f, 0.f};
      if (node < N) v = x4[(size_t)node * 32 + (i & 31)];
      xs4[i] = v;
    }
    __syncthreads();
    float4 acc0 = {0,0,0,0}, acc1 = {0,0,0,0}, acc2 = {0,0,0,0}, acc3 = {0,0,0,0};
    const float* xrow = &xs[tr * 4 * 128];
#pragma unroll 4
    for (int k = 0; k < 128; ++k) {
      float4 w4 = *(const float4*)&wS[k * 128 + tc * 4];
      float x0 = xrow[k], x1 = xrow[128 + k], x2 = xrow[256 + k], x3 = xrow[384 + k];
      acc0.x += x0 * w4.x; acc0.y += x0 * w4.y; acc0.z += x0 * w4.z; acc0.w += x0 * w4.w;
      acc1.x += x1 * w4.x; acc1.y += x1 * w4.y; acc1.z += x1 * w4.z; acc1.w += x1 * w4.w;
      acc2.x += x2 * w4.x; acc2.y += x2 * w4.y; acc2.z += x2 * w4.z; acc2.w += x2 * w4.w;
      acc3.x += x3 * w4.x; acc3.y += x3 * w4.y; acc3.z += x3 * w4.z; acc3.w += x3 * w4.w;
    }
    float* dp = (tc < 16) ? xl : xr;
    int j4 = (tc & 15) * 4;
    int nb = base + tr * 4;
    if (nb + 0 < N) *(float4*)&dp[(size_t)(nb + 0) * 64 + j4] = acc0;
    if (nb + 1 < N) *(float4*)&dp[(size_t)(nb + 1) * 64 + j4] = acc1;
    if (nb + 2 < N) *(float4*)&dp[(size_t)(nb + 2) * 64 + j4] = acc2;
    if (nb + 3 < N) *(float4*)&dp[(size_t)(nb + 3) * 64 + j4] = acc3;
    __syncthreads();
  }
}

// ------------------------------------------------- layer2 node transform (64 -> 32|32)
__global__ __launch_bounds__(256) void transform2_k(
    const float* __restrict__ h, const float* __restrict__ wl, const float* __restrict__ wr,
    float* __restrict__ xl, float* __restrict__ xr, int N) {
  __shared__ float wS[64 * 64];
  __shared__ float xs[64 * 64];
  int t = threadIdx.x;
  for (int i = t; i < 64 * 32; i += 256) {
    int k = i >> 5, j = i & 31;
    wS[k * 64 + j]      = wl[i];
    wS[k * 64 + 32 + j] = wr[i];
  }
  __syncthreads();
  int tc = t & 15;
  int tr = t >> 4;
  int ntiles = (N + 63) >> 6;
  for (int tile = blockIdx.x; tile < ntiles; tile += gridDim.x) {
    int base = tile << 6;
    const float4* h4 = (const float4*)h;
    float4* xs4 = (float4*)xs;
    for (int i = t; i < 1024; i += 256) {
      int node = base + (i >> 4);
      float4 v = {0.f, 0.f, 0.f, 0.f};
      if (node < N) v = h4[(size_t)node * 16 + (i & 15)];
      xs4[i] = v;
    }
    __syncthreads();
    float4 acc0 = {0,0,0,0}, acc1 = {0,0,0,0}, acc2 = {0,0,0,0}, acc3 = {0,0,0,0};
    const float* xrow = &xs[tr * 4 * 64];
#pragma unroll 4
    for (int k = 0; k < 64; ++k) {
      float4 w4 = *(const float4*)&wS[k * 64 + tc * 4];
      float x0 = xrow[k], x1 = xrow[64 + k], x2 = xrow[128 + k], x3 = xrow[192 + k];
      acc0.x += x0 * w4.x; acc0.y += x0 * w4.y; acc0.z += x0 * w4.z; acc0.w += x0 * w4.w;
      acc1.x += x1 * w4.x; acc1.y += x1 * w4.y; acc1.z += x1 * w4.z; acc1.w += x1 * w4.w;
      acc2.x += x2 * w4.x; acc2.y += x2 * w4.y; acc2.z += x2 * w4.z; acc2.w += x2 * w4.w;
      acc3.x += x3 * w4.x; acc3.y += x3 * w4.y; acc3.z += x3 * w4.z; acc3.w += x3 * w4.w;
    }
    float* dp = (tc < 8) ? xl : xr;
    int j4 = (tc & 7) * 4;
    int nb = base + tr * 4;
    if (nb + 0 < N) *(float4*)&dp[(size_t)(nb + 0) * 32 + j4] = acc0;
    if (nb + 1 < N) *(float4*)&dp[(size_t)(nb + 1) * 32 + j4] = acc1;
    if (nb + 2 < N) *(float4*)&dp[(size_t)(nb + 2) * 32 + j4] = acc2;
    if (nb + 3 < N) *(float4*)&dp[(size_t)(nb + 3) * 32 + j4] = acc3;
    __syncthreads();
  }
}

// ------------------------------------------------- GAT layer1: one wave per node (pull)
// ea read sequentially (CSR-permuted fp16); xl prefetched 1 edge ahead (1 reg rotate).
__global__ __launch_bounds__(256) void gat1_k(
    const int* __restrict__ rowptr, const int* __restrict__ csr_src,
    const uint4* __restrict__ ea_h, const float* __restrict__ we,
    const float* __restrict__ att, const float* __restrict__ b,
    const float* __restrict__ xl, const float* __restrict__ xr,
    float* __restrict__ h, int N) {
  int t = threadIdx.x;
  int lane = t & 63;
  float wreg[16];
#pragma unroll
  for (int k = 0; k < 16; ++k) wreg[k] = we[k * 64 + lane];
  float att_r = att[lane];
  float b_r = b[lane];
  int wid = (blockIdx.x * blockDim.x + t) >> 6;
  int nwaves = (gridDim.x * blockDim.x) >> 6;
  for (int n = wid; n < N; n += nwaves) {
    float xr_v = xr[(size_t)n * 64 + lane];
    float xl_s = xl[(size_t)n * 64 + lane];
    float num = 0.f, den = 0.f, efsum = 0.f;
    int rs = __builtin_amdgcn_readfirstlane(rowptr[n]);
    int re = __builtin_amdgcn_readfirstlane(rowptr[n + 1]);
    for (int base = rs; base < re; base += 64) {
      int cnt = min(64, re - base);
      int s_l = 0;
      if (lane < cnt) s_l = csr_src[base + lane];
      int s0 = __shfl(s_l, 0);
      float xcur = xl[(size_t)s0 * 64 + lane];
      for (int i = 0; i < cnt; ++i) {
        int sn = __shfl(s_l, min(i + 1, cnt - 1));
        float xnxt = xl[(size_t)sn * 64 + lane];
        const uint4* ep = ea_h + (size_t)(base + i) * 2;
        uint4 u0 = ep[0], u1 = ep[1];
        const __half2* hp0 = (const __half2*)&u0;
        const __half2* hp1 = (const __half2*)&u1;
        float2 q0 = __half22float2(hp0[0]), q1 = __half22float2(hp0[1]);
        float2 q2 = __half22float2(hp0[2]), q3 = __half22float2(hp0[3]);
        float2 q4 = __half22float2(hp1[0]), q5 = __half22float2(hp1[1]);
        float2 q6 = __half22float2(hp1[2]), q7 = __half22float2(hp1[3]);
        float ef2 = q0.x*wreg[0] + q0.y*wreg[1] + q1.x*wreg[2] + q1.y*wreg[3]
                  + q2.x*wreg[4] + q2.y*wreg[5] + q3.x*wreg[6] + q3.y*wreg[7]
                  + q4.x*wreg[8] + q4.y*wreg[9] + q5.x*wreg[10] + q5.y*wreg[11]
                  + q6.x*wreg[12] + q6.y*wreg[13] + q7.x*wreg[14] + q7.y*wreg[15];
        efsum += ef2;
        float mm = xcur + xr_v + ef2;
        mm = (mm > 0.f) ? mm : NEG_SLOPE * mm;
        float s2 = mm * att_r;
#pragma unroll
        for (int off = 1; off < 32; off <<= 1) s2 += __shfl_xor(s2, off);
        float e2 = __expf(s2);
        num += e2 * xcur;
        den += e2;
        xcur = xnxt;
      }
    }
    // self loop: ef_self = mean(ea@we) = efsum/deg
    int deg = re - rs;
    float ef_self = efsum / fmaxf((float)deg, 1.f);
    float mm = xl_s + xr_v + ef_self;
    mm = (mm > 0.f) ? mm : NEG_SLOPE * mm;
    float s2 = mm * att_r;
#pragma unroll
    for (int off = 1; off < 32; off <<= 1) s2 += __shfl_xor(s2, off);
    float e2 = __expf(s2);
    num += e2 * xl_s;
    den += e2;
    h[(size_t)n * 64 + lane] = fmaxf(num / fmaxf(den, 1e-16f) + b_r, 0.f);
  }
}

// ------------------------------------------------- GAT layer2: half-wave per node
__global__ __launch_bounds__(256) void gat2_k(
    const int* __restrict__ rowptr, const int* __restrict__ csr_src,
    const uint4* __restrict__ ea_h, const float* __restrict__ we,
    const float* __restrict__ att, const float* __restrict__ b,
    const float* __restrict__ xl, const float* __restrict__ xr,
    float* __restrict__ h, int N) {
  int t = threadIdx.x;
  int lane = t & 63;
  int c = lane & 31;
  int half = lane >> 5;
  int hbase = lane & 32;
  float wreg[16];
#pragma unroll
  for (int k = 0; k < 16; ++k) wreg[k] = we[k * 32 + c];
  float att_r = att[c];
  float b_r = b[c];
  int wid = (blockIdx.x * blockDim.x + t) >> 6;
  int nwaves = (gridDim.x * blockDim.x) >> 6;
  for (int np = wid; np * 2 < N; np += nwaves) {
    int n = np * 2 + half;
    if (n >= N) continue;
    float xr_v = xr[(size_t)n * 32 + c];
    float xl_s = xl[(size_t)n * 32 + c];
    float num = 0.f, den = 0.f, efsum = 0.f;
    int rs = rowptr[n], re = rowptr[n + 1];
    for (int base = rs; base < re; base += 32) {
      int cnt = min(32, re - base);
      int s_l = 0;
      if (c < cnt) s_l = csr_src[base + c];
      int s0 = __shfl(s_l, hbase);
      float xcur = xl[(size_t)s0 * 32 + c];
      for (int i = 0; i < cnt; ++i) {
        int sn = __shfl(s_l, hbase + min(i + 1, cnt - 1));
        float xnxt = xl[(size_t)sn * 32 + c];
        const uint4* ep = ea_h + (size_t)(base + i) * 2;
        uint4 u0 = ep[0], u1 = ep[1];
        const __half2* hp0 = (const __half2*)&u0;
        const __half2* hp1 = (const __half2*)&u1;
        float2 q0 = __half22float2(hp0[0]), q1 = __half22float2(hp0[1]);
        float2 q2 = __half22float2(hp0[2]), q3 = __half22float2(hp0[3]);
        float2 q4 = __half22float2(hp1[0]), q5 = __half22float2(hp1[1]);
        float2 q6 = __half22float2(hp1[2]), q7 = __half22float2(hp1[3]);
        float ef2 = q0.x*wreg[0] + q0.y*wreg[1] + q1.x*wreg[2] + q1.y*wreg[3]
                  + q2.x*wreg[4] + q2.y*wreg[5] + q3.x*wreg[6] + q3.y*wreg[7]
                  + q4.x*wreg[8] + q4.y*wreg[9] + q5.x*wreg[10] + q5.y*wreg[11]
                  + q6.x*wreg[12] + q6.y*wreg[13] + q7.x*wreg[14] + q7.y*wreg[15];
        efsum += ef2;
        float mm = xcur + xr_v + ef2;
        mm = (mm > 0.f) ? mm : NEG_SLOPE * mm;
        float s2 = mm * att_r;
#pragma unroll
        for (int off = 1; off < 32; off <<= 1) s2 += __shfl_xor(s2, off);
        float e2 = __expf(s2);
        num += e2 * xcur;
        den += e2;
        xcur = xnxt;
      }
    }
    int deg = re - rs;
    float ef_self = efsum / fmaxf((float)deg, 1.f);
    float mm = xl_s + xr_v + ef_self;
    mm = (mm > 0.f) ? mm : NEG_SLOPE * mm;
    float s2 = mm * att_r;
#pragma unroll
    for (int off = 1; off < 32; off <<= 1) s2 += __shfl_xor(s2, off);
    float e2 = __expf(s2);
    num += e2 * xl_s;
    den += e2;
    h[(size_t)n * 32 + c] = fmaxf(num / fmaxf(den, 1e-16f) + b_r, 0.f);
  }
}

// ------------------------------------------------- fused mean-pool + fc
__global__ __launch_bounds__(256) void pool_fc_k(
    const float* __restrict__ h, const int* __restrict__ batch,
    const float* __restrict__ wfc, const float* __restrict__ bfc,
    float* __restrict__ out, int N) {
  int g = blockIdx.x;
  __shared__ int srange[2];
  __shared__ float part[8][32];
  int t = threadIdx.x;
  if (t < 2) {
    int key = g + t;
    int lo = 0, hi = N;
    while (lo < hi) { int mid = (lo + hi) >> 1; if (batch[mid] < key) lo = mid + 1; else hi = mid; }
    srange[t] = lo;
  }
  __syncthreads();
  int rs = srange[0], re = srange[1];
  int c = t & 31, sub = t >> 5;
  float acc = 0.f;
  for (int n = rs + sub; n < re; n += 8) acc += h[(size_t)n * 32 + c];
  part[sub][c] = acc;
  __syncthreads();
  if (sub == 0) {
    float s = part[0][c];
#pragma unroll
    for (int i = 1; i < 8; ++i) s += part[i][c];
    part[0][c] = s / fmaxf((float)(re - rs), 1.f);
  }
  __syncthreads();
  if (sub == 0) {
    float a = 0.f;
#pragma unroll
    for (int k = 0; k < 32; ++k) a += part[0][k] * wfc[k * 32 + c];
    out[g * 32 + c] = a + bfc[c];
  }
}

// ----------------------------------------------------------------- launcher
extern "C" void kernel_launch(void* const* d_in, const int* in_sizes, int n_in,
                              void* d_out, int out_size, void* d_ws, size_t ws_size,
                              hipStream_t stream) {
  const float* x   = (const float*)d_in[0];
  const int*   ei  = (const int*)d_in[1];
  const float* ea  = (const float*)d_in[2];
  const int*   bat = (const int*)d_in[3];
  const float* wl1 = (const float*)d_in[4];
  const float* wr1 = (const float*)d_in[5];
  const float* we1 = (const float*)d_in[6];
  const float* at1 = (const float*)d_in[7];
  const float* b1  = (const float*)d_in[8];
  const float* wl2 = (const float*)d_in[9];
  const float* wr2 = (const float*)d_in[10];
  const float* we2 = (const float*)d_in[11];
  const float* at2 = (const float*)d_in[12];
  const float* b2  = (const float*)d_in[13];
  const float* wfc = (const float*)d_in[14];
  const float* bfc = (const float*)d_in[15];

  const int N = in_sizes[0] / 128;
  const int E = in_sizes[1] / 2;
  const int G = 256;
  const int* srcA = ei;
  const int* dstA = ei + E;

  // ---- workspace layout (~110 MB) ----
  uint4* ea_h   = (uint4*)d_ws;                      // E*2 uint4 (fp16 attrs, 51.2MB)
  float* xl1    = (float*)(ea_h + (size_t)E * 2);    // N*64
  float* xr1    = xl1 + (size_t)N * 64;              // N*64
  int*   deg    = (int*)(xr1 + (size_t)N * 64);      // N
  int*   rowptr = deg + N;                           // N+1
  int*   cursor = rowptr + (N + 1);                  // N
  int*   aux    = cursor + N;                        // 512
  int*   csr_src= aux + 512;                         // E
  float* h1     = xr1;                               // in-place over xr1
  float* xl2    = xl1;                               // N*32
  float* xr2    = xl1 + (size_t)N * 32;              // N*32
  float* h2     = xr2;                               // in-place over xr2

  const int naux = (N + 255) / 256;

  // ---- CSR build + ea permute ----
  hipMemsetAsync(deg, 0, (size_t)N * sizeof(int), stream);
  deg_count_k<<<(E + 255) / 256, 256, 0, stream>>>(dstA, deg, E);
  scan1_k<<<naux, 256, 0, stream>>>(deg, rowptr, aux, N);
  scan2_k<<<1, 512, 0, stream>>>(aux, naux);
  scan3_k<<<(N + 256) / 256, 256, 0, stream>>>(rowptr, cursor, aux, N, E);
  scatter_k<<<(E + 255) / 256, 256, 0, stream>>>(srcA, dstA, ea, cursor, csr_src, ea_h, E);

  // ---- layer 1 ----
  transform1_k<<<2048, 256, 0, stream>>>(x, wl1, wr1, xl1, xr1, N);
  gat1_k<<<8192, 256, 0, stream>>>(rowptr, csr_src, ea_h, we1, at1, b1,
                                   xl1, xr1, h1, N);

  // ---- layer 2 ----
  transform2_k<<<1024, 256, 0, stream>>>(h1, wl2, wr2, xl2, xr2, N);
  gat2_k<<<8192, 256, 0, stream>>>(rowptr, csr_src, ea_h, we2, at2, b2,
                                   xl2, xr2, h2, N);

  // ---- fused pool + fc ----
  pool_fc_k<<<G, 256, 0, stream>>>(h2, bat, wfc, bfc, (float*)d_out, N);
}

// Round 10
// 538.678 us; speedup vs baseline: 1.3629x; 1.1273x over previous
//
#include <hip/hip_runtime.h>
#include <hip/hip_bf16.h>
#include <hip/hip_fp16.h>

#define NEG_SLOPE 0.2f

typedef _Float16 h2v __attribute__((ext_vector_type(2)));

// ------------------------------------------------------------ CSR build
__global__ void deg_count_k(const int* __restrict__ dstA, int* __restrict__ deg, int E) {
  int e = blockIdx.x * blockDim.x + threadIdx.x;
  if (e < E) atomicAdd(&deg[dstA[e]], 1);
}

// exclusive scan, 3 phases (N <= 512*256)
__global__ void scan1_k(const int* __restrict__ deg, int* __restrict__ rowptr,
                        int* __restrict__ aux, int N) {
  __shared__ int sh[256];
  int t = threadIdx.x, i = blockIdx.x * 256 + t;
  int v = (i < N) ? deg[i] : 0;
  sh[t] = v; __syncthreads();
  for (int off = 1; off < 256; off <<= 1) {
    int x = (t >= off) ? sh[t - off] : 0;
    __syncthreads();
    sh[t] += x;
    __syncthreads();
  }
  if (i < N) rowptr[i] = sh[t] - v;
  if (t == 255) aux[blockIdx.x] = sh[255];
}

__global__ void scan2_k(int* __restrict__ aux, int naux) {
  __shared__ int sh[512];
  int t = threadIdx.x;
  int v = (t < naux) ? aux[t] : 0;
  sh[t] = v; __syncthreads();
  for (int off = 1; off < 512; off <<= 1) {
    int x = (t >= off) ? sh[t - off] : 0;
    __syncthreads();
    sh[t] += x;
    __syncthreads();
  }
  if (t < naux) aux[t] = sh[t] - v;
}

__global__ void scan3_k(int* __restrict__ rowptr, int* __restrict__ cursor,
                        const int* __restrict__ aux, int N, int E) {
  int i = blockIdx.x * blockDim.x + threadIdx.x;
  if (i < N) {
    int r = rowptr[i] + aux[i >> 8];
    rowptr[i] = r;
    cursor[i] = r;
  } else if (i == N) {
    rowptr[N] = E;
  }
}

// scatter: builds csr_src AND permuted fp16 edge-attrs (CSR order, 32B/edge)
__global__ void scatter_k(const int* __restrict__ srcA, const int* __restrict__ dstA,
                          const float* __restrict__ ea, int* __restrict__ cursor,
                          int* __restrict__ csr_src, uint4* __restrict__ ea_h, int E) {
  int e = blockIdx.x * blockDim.x + threadIdx.x;
  if (e >= E) return;
  int pos = atomicAdd(&cursor[dstA[e]], 1);
  csr_src[pos] = srcA[e];
  const float* p = ea + (size_t)e * 16;
  union { __half2 h2[8]; uint4 u[2]; } cv;
#pragma unroll
  for (int k = 0; k < 8; ++k) cv.h2[k] = __floats2half2_rn(p[2 * k], p[2 * k + 1]);
  uint4* d = ea_h + (size_t)pos * 2;
  d[0] = cv.u[0];
  d[1] = cv.u[1];
}

// ------------------------------------------------- layer1 node transform (128 -> 64|64)
__global__ __launch_bounds__(256) void transform1_k(
    const float* __restrict__ x, const float* __restrict__ wl, const float* __restrict__ wr,
    float* __restrict__ xl, float* __restrict__ xr, int N) {
  __shared__ float wS[128 * 128];
  __shared__ float xs[32 * 128];
  int t = threadIdx.x;
  for (int i = t; i < 128 * 64; i += 256) {
    int k = i >> 6, j = i & 63;
    wS[k * 128 + j]      = wl[i];
    wS[k * 128 + 64 + j] = wr[i];
  }
  __syncthreads();
  int tc = t & 31;
  int tr = t >> 5;
  int ntiles = (N + 31) >> 5;
  for (int tile = blockIdx.x; tile < ntiles; tile += gridDim.x) {
    int base = tile << 5;
    const float4* x4 = (const float4*)x;
    float4* xs4 = (float4*)xs;
    for (int i = t; i < 1024; i += 256) {
      int node = base + (i >> 5);
      float4 v = {0.f, 0.f, 0.f, 0.f};
      if (node < N) v = x4[(size_t)node * 32 + (i & 31)];
      xs4[i] = v;
    }
    __syncthreads();
    float4 acc0 = {0,0,0,0}, acc1 = {0,0,0,0}, acc2 = {0,0,0,0}, acc3 = {0,0,0,0};
    const float* xrow = &xs[tr * 4 * 128];
#pragma unroll 4
    for (int k = 0; k < 128; ++k) {
      float4 w4 = *(const float4*)&wS[k * 128 + tc * 4];
      float x0 = xrow[k], x1 = xrow[128 + k], x2 = xrow[256 + k], x3 = xrow[384 + k];
      acc0.x += x0 * w4.x; acc0.y += x0 * w4.y; acc0.z += x0 * w4.z; acc0.w += x0 * w4.w;
      acc1.x += x1 * w4.x; acc1.y += x1 * w4.y; acc1.z += x1 * w4.z; acc1.w += x1 * w4.w;
      acc2.x += x2 * w4.x; acc2.y += x2 * w4.y; acc2.z += x2 * w4.z; acc2.w += x2 * w4.w;
      acc3.x += x3 * w4.x; acc3.y += x3 * w4.y; acc3.z += x3 * w4.z; acc3.w += x3 * w4.w;
    }
    float* dp = (tc < 16) ? xl : xr;
    int j4 = (tc & 15) * 4;
    int nb = base + tr * 4;
    if (nb + 0 < N) *(float4*)&dp[(size_t)(nb + 0) * 64 + j4] = acc0;
    if (nb + 1 < N) *(float4*)&dp[(size_t)(nb + 1) * 64 + j4] = acc1;
    if (nb + 2 < N) *(float4*)&dp[(size_t)(nb + 2) * 64 + j4] = acc2;
    if (nb + 3 < N) *(float4*)&dp[(size_t)(nb + 3) * 64 + j4] = acc3;
    __syncthreads();
  }
}

// ------------------------------------------------- layer2 node transform (64 -> 32|32)
__global__ __launch_bounds__(256) void transform2_k(
    const float* __restrict__ h, const float* __restrict__ wl, const float* __restrict__ wr,
    float* __restrict__ xl, float* __restrict__ xr, int N) {
  __shared__ float wS[64 * 64];
  __shared__ float xs[64 * 64];
  int t = threadIdx.x;
  for (int i = t; i < 64 * 32; i += 256) {
    int k = i >> 5, j = i & 31;
    wS[k * 64 + j]      = wl[i];
    wS[k * 64 + 32 + j] = wr[i];
  }
  __syncthreads();
  int tc = t & 15;
  int tr = t >> 4;
  int ntiles = (N + 63) >> 6;
  for (int tile = blockIdx.x; tile < ntiles; tile += gridDim.x) {
    int base = tile << 6;
    const float4* h4 = (const float4*)h;
    float4* xs4 = (float4*)xs;
    for (int i = t; i < 1024; i += 256) {
      int node = base + (i >> 4);
      float4 v = {0.f, 0.f, 0.f, 0.f};
      if (node < N) v = h4[(size_t)node * 16 + (i & 15)];
      xs4[i] = v;
    }
    __syncthreads();
    float4 acc0 = {0,0,0,0}, acc1 = {0,0,0,0}, acc2 = {0,0,0,0}, acc3 = {0,0,0,0};
    const float* xrow = &xs[tr * 4 * 64];
#pragma unroll 4
    for (int k = 0; k < 64; ++k) {
      float4 w4 = *(const float4*)&wS[k * 64 + tc * 4];
      float x0 = xrow[k], x1 = xrow[64 + k], x2 = xrow[128 + k], x3 = xrow[192 + k];
      acc0.x += x0 * w4.x; acc0.y += x0 * w4.y; acc0.z += x0 * w4.z; acc0.w += x0 * w4.w;
      acc1.x += x1 * w4.x; acc1.y += x1 * w4.y; acc1.z += x1 * w4.z; acc1.w += x1 * w4.w;
      acc2.x += x2 * w4.x; acc2.y += x2 * w4.y; acc2.z += x2 * w4.z; acc2.w += x2 * w4.w;
      acc3.x += x3 * w4.x; acc3.y += x3 * w4.y; acc3.z += x3 * w4.z; acc3.w += x3 * w4.w;
    }
    float* dp = (tc < 8) ? xl : xr;
    int j4 = (tc & 7) * 4;
    int nb = base + tr * 4;
    if (nb + 0 < N) *(float4*)&dp[(size_t)(nb + 0) * 32 + j4] = acc0;
    if (nb + 1 < N) *(float4*)&dp[(size_t)(nb + 1) * 32 + j4] = acc1;
    if (nb + 2 < N) *(float4*)&dp[(size_t)(nb + 2) * 32 + j4] = acc2;
    if (nb + 3 < N) *(float4*)&dp[(size_t)(nb + 3) * 32 + j4] = acc3;
    __syncthreads();
  }
}

// ------------------------------------------------- GAT layer1: one wave per node (pull)
// ea sequential fp16 + v_dot2_f32_f16 (we also fp16): 8 fdot2 replaces 16 cvt + 16 fma.
__global__ __launch_bounds__(256) void gat1_k(
    const int* __restrict__ rowptr, const int* __restrict__ csr_src,
    const uint4* __restrict__ ea_h, const float* __restrict__ we,
    const float* __restrict__ att, const float* __restrict__ b,
    const float* __restrict__ xl, const float* __restrict__ xr,
    float* __restrict__ h, int N) {
  int t = threadIdx.x;
  int lane = t & 63;
  h2v wh[8];
#pragma unroll
  for (int k = 0; k < 8; ++k) {
    wh[k].x = (_Float16)we[(2 * k) * 64 + lane];
    wh[k].y = (_Float16)we[(2 * k + 1) * 64 + lane];
  }
  float att_r = att[lane];
  float b_r = b[lane];
  int wid = (blockIdx.x * blockDim.x + t) >> 6;
  int nwaves = (gridDim.x * blockDim.x) >> 6;
  for (int n = wid; n < N; n += nwaves) {
    float xr_v = xr[(size_t)n * 64 + lane];
    float xl_s = xl[(size_t)n * 64 + lane];
    float num = 0.f, den = 0.f, efsum = 0.f;
    int rs = __builtin_amdgcn_readfirstlane(rowptr[n]);
    int re = __builtin_amdgcn_readfirstlane(rowptr[n + 1]);
    for (int base = rs; base < re; base += 64) {
      int cnt = min(64, re - base);
      int s_l = 0;
      if (lane < cnt) s_l = csr_src[base + lane];
      int s0 = __shfl(s_l, 0);
      float xcur = xl[(size_t)s0 * 64 + lane];
      for (int i = 0; i < cnt; ++i) {
        int sn = __shfl(s_l, min(i + 1, cnt - 1));
        float xnxt = xl[(size_t)sn * 64 + lane];
        const uint4* ep = ea_h + (size_t)(base + i) * 2;
        union { uint4 u; h2v h[4]; } u0, u1;
        u0.u = ep[0]; u1.u = ep[1];
        float efa = 0.f, efb = 0.f;
        efa = __builtin_amdgcn_fdot2(u0.h[0], wh[0], efa, false);
        efb = __builtin_amdgcn_fdot2(u0.h[1], wh[1], efb, false);
        efa = __builtin_amdgcn_fdot2(u0.h[2], wh[2], efa, false);
        efb = __builtin_amdgcn_fdot2(u0.h[3], wh[3], efb, false);
        efa = __builtin_amdgcn_fdot2(u1.h[0], wh[4], efa, false);
        efb = __builtin_amdgcn_fdot2(u1.h[1], wh[5], efb, false);
        efa = __builtin_amdgcn_fdot2(u1.h[2], wh[6], efa, false);
        efb = __builtin_amdgcn_fdot2(u1.h[3], wh[7], efb, false);
        float ef2 = efa + efb;
        efsum += ef2;
        float mm = xcur + xr_v + ef2;
        mm = (mm > 0.f) ? mm : NEG_SLOPE * mm;
        float s2 = mm * att_r;
#pragma unroll
        for (int off = 1; off < 32; off <<= 1) s2 += __shfl_xor(s2, off);
        float e2 = __expf(s2);
        num += e2 * xcur;
        den += e2;
        xcur = xnxt;
      }
    }
    // self loop: ef_self = mean(ea@we) = efsum/deg
    int deg = re - rs;
    float ef_self = efsum / fmaxf((float)deg, 1.f);
    float mm = xl_s + xr_v + ef_self;
    mm = (mm > 0.f) ? mm : NEG_SLOPE * mm;
    float s2 = mm * att_r;
#pragma unroll
    for (int off = 1; off < 32; off <<= 1) s2 += __shfl_xor(s2, off);
    float e2 = __expf(s2);
    num += e2 * xl_s;
    den += e2;
    h[(size_t)n * 64 + lane] = fmaxf(num / fmaxf(den, 1e-16f) + b_r, 0.f);
  }
}

// ------------------------------------------------- GAT layer2: half-wave per node
__global__ __launch_bounds__(256) void gat2_k(
    const int* __restrict__ rowptr, const int* __restrict__ csr_src,
    const uint4* __restrict__ ea_h, const float* __restrict__ we,
    const float* __restrict__ att, const float* __restrict__ b,
    const float* __restrict__ xl, const float* __restrict__ xr,
    float* __restrict__ h, int N) {
  int t = threadIdx.x;
  int lane = t & 63;
  int c = lane & 31;
  int half = lane >> 5;
  int hbase = lane & 32;
  h2v wh[8];
#pragma unroll
  for (int k = 0; k < 8; ++k) {
    wh[k].x = (_Float16)we[(2 * k) * 32 + c];
    wh[k].y = (_Float16)we[(2 * k + 1) * 32 + c];
  }
  float att_r = att[c];
  float b_r = b[c];
  int wid = (blockIdx.x * blockDim.x + t) >> 6;
  int nwaves = (gridDim.x * blockDim.x) >> 6;
  for (int np = wid; np * 2 < N; np += nwaves) {
    int n = np * 2 + half;
    if (n >= N) continue;
    float xr_v = xr[(size_t)n * 32 + c];
    float xl_s = xl[(size_t)n * 32 + c];
    float num = 0.f, den = 0.f, efsum = 0.f;
    int rs = rowptr[n], re = rowptr[n + 1];
    for (int base = rs; base < re; base += 32) {
      int cnt = min(32, re - base);
      int s_l = 0;
      if (c < cnt) s_l = csr_src[base + c];
      int s0 = __shfl(s_l, hbase);
      float xcur = xl[(size_t)s0 * 32 + c];
      for (int i = 0; i < cnt; ++i) {
        int sn = __shfl(s_l, hbase + min(i + 1, cnt - 1));
        float xnxt = xl[(size_t)sn * 32 + c];
        const uint4* ep = ea_h + (size_t)(base + i) * 2;
        union { uint4 u; h2v h[4]; } u0, u1;
        u0.u = ep[0]; u1.u = ep[1];
        float efa = 0.f, efb = 0.f;
        efa = __builtin_amdgcn_fdot2(u0.h[0], wh[0], efa, false);
        efb = __builtin_amdgcn_fdot2(u0.h[1], wh[1], efb, false);
        efa = __builtin_amdgcn_fdot2(u0.h[2], wh[2], efa, false);
        efb = __builtin_amdgcn_fdot2(u0.h[3], wh[3], efb, false);
        efa = __builtin_amdgcn_fdot2(u1.h[0], wh[4], efa, false);
        efb = __builtin_amdgcn_fdot2(u1.h[1], wh[5], efb, false);
        efa = __builtin_amdgcn_fdot2(u1.h[2], wh[6], efa, false);
        efb = __builtin_amdgcn_fdot2(u1.h[3], wh[7], efb, false);
        float ef2 = efa + efb;
        efsum += ef2;
        float mm = xcur + xr_v + ef2;
        mm = (mm > 0.f) ? mm : NEG_SLOPE * mm;
        float s2 = mm * att_r;
#pragma unroll
        for (int off = 1; off < 32; off <<= 1) s2 += __shfl_xor(s2, off);
        float e2 = __expf(s2);
        num += e2 * xcur;
        den += e2;
        xcur = xnxt;
      }
    }
    int deg = re - rs;
    float ef_self = efsum / fmaxf((float)deg, 1.f);
    float mm = xl_s + xr_v + ef_self;
    mm = (mm > 0.f) ? mm : NEG_SLOPE * mm;
    float s2 = mm * att_r;
#pragma unroll
    for (int off = 1; off < 32; off <<= 1) s2 += __shfl_xor(s2, off);
    float e2 = __expf(s2);
    num += e2 * xl_s;
    den += e2;
    h[(size_t)n * 32 + c] = fmaxf(num / fmaxf(den, 1e-16f) + b_r, 0.f);
  }
}

// ------------------------------------------------- fused mean-pool + fc
__global__ __launch_bounds__(256) void pool_fc_k(
    const float* __restrict__ h, const int* __restrict__ batch,
    const float* __restrict__ wfc, const float* __restrict__ bfc,
    float* __restrict__ out, int N) {
  int g = blockIdx.x;
  __shared__ int srange[2];
  __shared__ float part[8][32];
  int t = threadIdx.x;
  if (t < 2) {
    int key = g + t;
    int lo = 0, hi = N;
    while (lo < hi) { int mid = (lo + hi) >> 1; if (batch[mid] < key) lo = mid + 1; else hi = mid; }
    srange[t] = lo;
  }
  __syncthreads();
  int rs = srange[0], re = srange[1];
  int c = t & 31, sub = t >> 5;
  float acc = 0.f;
  for (int n = rs + sub; n < re; n += 8) acc += h[(size_t)n * 32 + c];
  part[sub][c] = acc;
  __syncthreads();
  if (sub == 0) {
    float s = part[0][c];
#pragma unroll
    for (int i = 1; i < 8; ++i) s += part[i][c];
    part[0][c] = s / fmaxf((float)(re - rs), 1.f);
  }
  __syncthreads();
  if (sub == 0) {
    float a = 0.f;
#pragma unroll
    for (int k = 0; k < 32; ++k) a += part[0][k] * wfc[k * 32 + c];
    out[g * 32 + c] = a + bfc[c];
  }
}

// ----------------------------------------------------------------- launcher
extern "C" void kernel_launch(void* const* d_in, const int* in_sizes, int n_in,
                              void* d_out, int out_size, void* d_ws, size_t ws_size,
                              hipStream_t stream) {
  const float* x   = (const float*)d_in[0];
  const int*   ei  = (const int*)d_in[1];
  const float* ea  = (const float*)d_in[2];
  const int*   bat = (const int*)d_in[3];
  const float* wl1 = (const float*)d_in[4];
  const float* wr1 = (const float*)d_in[5];
  const float* we1 = (const float*)d_in[6];
  const float* at1 = (const float*)d_in[7];
  const float* b1  = (const float*)d_in[8];
  const float* wl2 = (const float*)d_in[9];
  const float* wr2 = (const float*)d_in[10];
  const float* we2 = (const float*)d_in[11];
  const float* at2 = (const float*)d_in[12];
  const float* b2  = (const float*)d_in[13];
  const float* wfc = (const float*)d_in[14];
  const float* bfc = (const float*)d_in[15];

  const int N = in_sizes[0] / 128;
  const int E = in_sizes[1] / 2;
  const int G = 256;
  const int* srcA = ei;
  const int* dstA = ei + E;

  // ---- workspace layout (~110 MB) ----
  uint4* ea_h   = (uint4*)d_ws;                      // E*2 uint4 (fp16 attrs)
  float* xl1    = (float*)(ea_h + (size_t)E * 2);    // N*64
  float* xr1    = xl1 + (size_t)N * 64;              // N*64
  int*   deg    = (int*)(xr1 + (size_t)N * 64);      // N
  int*   rowptr = deg + N;                           // N+1
  int*   cursor = rowptr + (N + 1);                  // N
  int*   aux    = cursor + N;                        // 512
  int*   csr_src= aux + 512;                         // E
  float* h1     = xr1;                               // in-place over xr1
  float* xl2    = xl1;                               // N*32
  float* xr2    = xl1 + (size_t)N * 32;              // N*32
  float* h2     = xr2;                               // in-place over xr2

  const int naux = (N + 255) / 256;

  // ---- CSR build + ea permute ----
  hipMemsetAsync(deg, 0, (size_t)N * sizeof(int), stream);
  deg_count_k<<<(E + 255) / 256, 256, 0, stream>>>(dstA, deg, E);
  scan1_k<<<naux, 256, 0, stream>>>(deg, rowptr, aux, N);
  scan2_k<<<1, 512, 0, stream>>>(aux, naux);
  scan3_k<<<(N + 256) / 256, 256, 0, stream>>>(rowptr, cursor, aux, N, E);
  scatter_k<<<(E + 255) / 256, 256, 0, stream>>>(srcA, dstA, ea, cursor, csr_src, ea_h, E);

  // ---- layer 1 ----
  transform1_k<<<2048, 256, 0, stream>>>(x, wl1, wr1, xl1, xr1, N);
  gat1_k<<<8192, 256, 0, stream>>>(rowptr, csr_src, ea_h, we1, at1, b1,
                                   xl1, xr1, h1, N);

  // ---- layer 2 ----
  transform2_k<<<1024, 256, 0, stream>>>(h1, wl2, wr2, xl2, xr2, N);
  gat2_k<<<8192, 256, 0, stream>>>(rowptr, csr_src, ea_h, we2, at2, b2,
                                   xl2, xr2, h2, N);

  // ---- fused pool + fc ----
  pool_fc_k<<<G, 256, 0, stream>>>(h2, bat, wfc, bfc, (float*)d_out, N);
}

// Round 11
// 533.022 us; speedup vs baseline: 1.3774x; 1.0106x over previous
//
#include <hip/hip_runtime.h>
#include <hip/hip_bf16.h>
#include <hip/hip_fp16.h>

#define NEG_SLOPE 0.2f

typedef _Float16 h2v __attribute__((ext_vector_type(2)));

// ------------------------------------------------------------ CSR build
__global__ void deg_count_k(const int* __restrict__ dstA, int* __restrict__ deg, int E) {
  int e = blockIdx.x * blockDim.x + threadIdx.x;
  if (e < E) atomicAdd(&deg[dstA[e]], 1);
}

// exclusive scan, 3 phases (N <= 512*256)
__global__ void scan1_k(const int* __restrict__ deg, int* __restrict__ rowptr,
                        int* __restrict__ aux, int N) {
  __shared__ int sh[256];
  int t = threadIdx.x, i = blockIdx.x * 256 + t;
  int v = (i < N) ? deg[i] : 0;
  sh[t] = v; __syncthreads();
  for (int off = 1; off < 256; off <<= 1) {
    int x = (t >= off) ? sh[t - off] : 0;
    __syncthreads();
    sh[t] += x;
    __syncthreads();
  }
  if (i < N) rowptr[i] = sh[t] - v;
  if (t == 255) aux[blockIdx.x] = sh[255];
}

__global__ void scan2_k(int* __restrict__ aux, int naux) {
  __shared__ int sh[512];
  int t = threadIdx.x;
  int v = (t < naux) ? aux[t] : 0;
  sh[t] = v; __syncthreads();
  for (int off = 1; off < 512; off <<= 1) {
    int x = (t >= off) ? sh[t - off] : 0;
    __syncthreads();
    sh[t] += x;
    __syncthreads();
  }
  if (t < naux) aux[t] = sh[t] - v;
}

__global__ void scan3_k(int* __restrict__ rowptr, int* __restrict__ cursor,
                        const int* __restrict__ aux, int N, int E) {
  int i = blockIdx.x * blockDim.x + threadIdx.x;
  if (i < N) {
    int r = rowptr[i] + aux[i >> 8];
    rowptr[i] = r;
    cursor[i] = r;
  } else if (i == N) {
    rowptr[N] = E;
  }
}

// scatter: builds csr_src AND permuted fp16 edge-attrs (CSR order, 32B/edge)
__global__ void scatter_k(const int* __restrict__ srcA, const int* __restrict__ dstA,
                          const float* __restrict__ ea, int* __restrict__ cursor,
                          int* __restrict__ csr_src, uint4* __restrict__ ea_h, int E) {
  int e = blockIdx.x * blockDim.x + threadIdx.x;
  if (e >= E) return;
  int pos = atomicAdd(&cursor[dstA[e]], 1);
  csr_src[pos] = srcA[e];
  const float* p = ea + (size_t)e * 16;
  union { __half2 h2[8]; uint4 u[2]; } cv;
#pragma unroll
  for (int k = 0; k < 8; ++k) cv.h2[k] = __floats2half2_rn(p[2 * k], p[2 * k + 1]);
  uint4* d = ea_h + (size_t)pos * 2;
  d[0] = cv.u[0];
  d[1] = cv.u[1];
}

// ------------------------------------------------- layer1 node transform (128 -> 64|64)
__global__ __launch_bounds__(256) void transform1_k(
    const float* __restrict__ x, const float* __restrict__ wl, const float* __restrict__ wr,
    float* __restrict__ xl, float* __restrict__ xr, int N) {
  __shared__ float wS[128 * 128];
  __shared__ float xs[32 * 128];
  int t = threadIdx.x;
  for (int i = t; i < 128 * 64; i += 256) {
    int k = i >> 6, j = i & 63;
    wS[k * 128 + j]      = wl[i];
    wS[k * 128 + 64 + j] = wr[i];
  }
  __syncthreads();
  int tc = t & 31;
  int tr = t >> 5;
  int ntiles = (N + 31) >> 5;
  for (int tile = blockIdx.x; tile < ntiles; tile += gridDim.x) {
    int base = tile << 5;
    const float4* x4 = (const float4*)x;
    float4* xs4 = (float4*)xs;
    for (int i = t; i < 1024; i += 256) {
      int node = base + (i >> 5);
      float4 v = {0.f, 0.f, 0.f, 0.f};
      if (node < N) v = x4[(size_t)node * 32 + (i & 31)];
      xs4[i] = v;
    }
    __syncthreads();
    float4 acc0 = {0,0,0,0}, acc1 = {0,0,0,0}, acc2 = {0,0,0,0}, acc3 = {0,0,0,0};
    const float* xrow = &xs[tr * 4 * 128];
#pragma unroll 4
    for (int k = 0; k < 128; ++k) {
      float4 w4 = *(const float4*)&wS[k * 128 + tc * 4];
      float x0 = xrow[k], x1 = xrow[128 + k], x2 = xrow[256 + k], x3 = xrow[384 + k];
      acc0.x += x0 * w4.x; acc0.y += x0 * w4.y; acc0.z += x0 * w4.z; acc0.w += x0 * w4.w;
      acc1.x += x1 * w4.x; acc1.y += x1 * w4.y; acc1.z += x1 * w4.z; acc1.w += x1 * w4.w;
      acc2.x += x2 * w4.x; acc2.y += x2 * w4.y; acc2.z += x2 * w4.z; acc2.w += x2 * w4.w;
      acc3.x += x3 * w4.x; acc3.y += x3 * w4.y; acc3.z += x3 * w4.z; acc3.w += x3 * w4.w;
    }
    float* dp = (tc < 16) ? xl : xr;
    int j4 = (tc & 15) * 4;
    int nb = base + tr * 4;
    if (nb + 0 < N) *(float4*)&dp[(size_t)(nb + 0) * 64 + j4] = acc0;
    if (nb + 1 < N) *(float4*)&dp[(size_t)(nb + 1) * 64 + j4] = acc1;
    if (nb + 2 < N) *(float4*)&dp[(size_t)(nb + 2) * 64 + j4] = acc2;
    if (nb + 3 < N) *(float4*)&dp[(size_t)(nb + 3) * 64 + j4] = acc3;
    __syncthreads();
  }
}

// ------------------------------------------------- layer2 node transform (64 -> 32|32)
__global__ __launch_bounds__(256) void transform2_k(
    const float* __restrict__ h, const float* __restrict__ wl, const float* __restrict__ wr,
    float* __restrict__ xl, float* __restrict__ xr, int N) {
  __shared__ float wS[64 * 64];
  __shared__ float xs[64 * 64];
  int t = threadIdx.x;
  for (int i = t; i < 64 * 32; i += 256) {
    int k = i >> 5, j = i & 31;
    wS[k * 64 + j]      = wl[i];
    wS[k * 64 + 32 + j] = wr[i];
  }
  __syncthreads();
  int tc = t & 15;
  int tr = t >> 4;
  int ntiles = (N + 63) >> 6;
  for (int tile = blockIdx.x; tile < ntiles; tile += gridDim.x) {
    int base = tile << 6;
    const float4* h4 = (const float4*)h;
    float4* xs4 = (float4*)xs;
    for (int i = t; i < 1024; i += 256) {
      int node = base + (i >> 4);
      float4 v = {0.f, 0.f, 0.f, 0.f};
      if (node < N) v = h4[(size_t)node * 16 + (i & 15)];
      xs4[i] = v;
    }
    __syncthreads();
    float4 acc0 = {0,0,0,0}, acc1 = {0,0,0,0}, acc2 = {0,0,0,0}, acc3 = {0,0,0,0};
    const float* xrow = &xs[tr * 4 * 64];
#pragma unroll 4
    for (int k = 0; k < 64; ++k) {
      float4 w4 = *(const float4*)&wS[k * 64 + tc * 4];
      float x0 = xrow[k], x1 = xrow[64 + k], x2 = xrow[128 + k], x3 = xrow[192 + k];
      acc0.x += x0 * w4.x; acc0.y += x0 * w4.y; acc0.z += x0 * w4.z; acc0.w += x0 * w4.w;
      acc1.x += x1 * w4.x; acc1.y += x1 * w4.y; acc1.z += x1 * w4.z; acc1.w += x1 * w4.w;
      acc2.x += x2 * w4.x; acc2.y += x2 * w4.y; acc2.z += x2 * w4.z; acc2.w += x2 * w4.w;
      acc3.x += x3 * w4.x; acc3.y += x3 * w4.y; acc3.z += x3 * w4.z; acc3.w += x3 * w4.w;
    }
    float* dp = (tc < 8) ? xl : xr;
    int j4 = (tc & 7) * 4;
    int nb = base + tr * 4;
    if (nb + 0 < N) *(float4*)&dp[(size_t)(nb + 0) * 32 + j4] = acc0;
    if (nb + 1 < N) *(float4*)&dp[(size_t)(nb + 1) * 32 + j4] = acc1;
    if (nb + 2 < N) *(float4*)&dp[(size_t)(nb + 2) * 32 + j4] = acc2;
    if (nb + 3 < N) *(float4*)&dp[(size_t)(nb + 3) * 32 + j4] = acc3;
    __syncthreads();
  }
}

// ------------------------------------------------- GAT layer1: one wave per node (pull)
// Blocked assignment (4 consecutive nodes/wave, exact divide) + 2-wide edge unroll
// with independent fdot2/butterfly/exp chains; tail via clamp+mask.
__global__ __launch_bounds__(256) void gat1_k(
    const int* __restrict__ rowptr, const int* __restrict__ csr_src,
    const uint4* __restrict__ ea_h, const float* __restrict__ we,
    const float* __restrict__ att, const float* __restrict__ b,
    const float* __restrict__ xl, const float* __restrict__ xr,
    float* __restrict__ h, int N) {
  int t = threadIdx.x;
  int lane = t & 63;
  h2v wh[8];
#pragma unroll
  for (int k = 0; k < 8; ++k) {
    wh[k].x = (_Float16)we[(2 * k) * 64 + lane];
    wh[k].y = (_Float16)we[(2 * k + 1) * 64 + lane];
  }
  float att_r = att[lane];
  float b_r = b[lane];
  int wid = (blockIdx.x * blockDim.x + t) >> 6;
  int n0 = wid * 4;
  for (int jj = 0; jj < 4; ++jj) {
    int n = n0 + jj;
    if (n >= N) break;
    float xr_v = xr[(size_t)n * 64 + lane];
    float xl_s = xl[(size_t)n * 64 + lane];
    float num = 0.f, den = 0.f, efsum = 0.f;
    int rs = __builtin_amdgcn_readfirstlane(rowptr[n]);
    int re = __builtin_amdgcn_readfirstlane(rowptr[n + 1]);
    for (int base = rs; base < re; base += 64) {
      int cnt = min(64, re - base);
      int s_l = 0;
      if (lane < cnt) s_l = csr_src[base + lane];
      for (int i = 0; i < cnt; i += 2) {
        int j1 = min(i + 1, cnt - 1);
        int sa = __shfl(s_l, i), sb = __shfl(s_l, j1);
        float xa = xl[(size_t)sa * 64 + lane];
        float xb = xl[(size_t)sb * 64 + lane];
        const uint4* epa = ea_h + (size_t)(base + i) * 2;
        const uint4* epb = ea_h + (size_t)(base + j1) * 2;
        union { uint4 u; h2v h[4]; } a0, a1, c0, c1;
        a0.u = epa[0]; a1.u = epa[1];
        c0.u = epb[0]; c1.u = epb[1];
        float fa0 = 0.f, fa1 = 0.f, fb0 = 0.f, fb1 = 0.f;
        fa0 = __builtin_amdgcn_fdot2(a0.h[0], wh[0], fa0, false);
        fb0 = __builtin_amdgcn_fdot2(c0.h[0], wh[0], fb0, false);
        fa1 = __builtin_amdgcn_fdot2(a0.h[1], wh[1], fa1, false);
        fb1 = __builtin_amdgcn_fdot2(c0.h[1], wh[1], fb1, false);
        fa0 = __builtin_amdgcn_fdot2(a0.h[2], wh[2], fa0, false);
        fb0 = __builtin_amdgcn_fdot2(c0.h[2], wh[2], fb0, false);
        fa1 = __builtin_amdgcn_fdot2(a0.h[3], wh[3], fa1, false);
        fb1 = __builtin_amdgcn_fdot2(c0.h[3], wh[3], fb1, false);
        fa0 = __builtin_amdgcn_fdot2(a1.h[0], wh[4], fa0, false);
        fb0 = __builtin_amdgcn_fdot2(c1.h[0], wh[4], fb0, false);
        fa1 = __builtin_amdgcn_fdot2(a1.h[1], wh[5], fa1, false);
        fb1 = __builtin_amdgcn_fdot2(c1.h[1], wh[5], fb1, false);
        fa0 = __builtin_amdgcn_fdot2(a1.h[2], wh[6], fa0, false);
        fb0 = __builtin_amdgcn_fdot2(c1.h[2], wh[6], fb0, false);
        fa1 = __builtin_amdgcn_fdot2(a1.h[3], wh[7], fa1, false);
        fb1 = __builtin_amdgcn_fdot2(c1.h[3], wh[7], fb1, false);
        float fa = fa0 + fa1, fb = fb0 + fb1;
        float ma = xa + xr_v + fa; ma = (ma > 0.f) ? ma : NEG_SLOPE * ma;
        float mb = xb + xr_v + fb; mb = (mb > 0.f) ? mb : NEG_SLOPE * mb;
        float ta = ma * att_r, tb = mb * att_r;
#pragma unroll
        for (int off = 1; off < 32; off <<= 1) {
          ta += __shfl_xor(ta, off);
          tb += __shfl_xor(tb, off);
        }
        float ga = __expf(ta), gb = __expf(tb);
        float kb = (i + 1 < cnt) ? 1.f : 0.f;
        num += ga * xa + kb * gb * xb;
        den += ga + kb * gb;
        efsum += fa + kb * fb;
      }
    }
    // self loop: ef_self = mean(ea@we) = efsum/deg
    int deg = re - rs;
    float ef_self = efsum / fmaxf((float)deg, 1.f);
    float mm = xl_s + xr_v + ef_self;
    mm = (mm > 0.f) ? mm : NEG_SLOPE * mm;
    float s2 = mm * att_r;
#pragma unroll
    for (int off = 1; off < 32; off <<= 1) s2 += __shfl_xor(s2, off);
    float e2 = __expf(s2);
    num += e2 * xl_s;
    den += e2;
    h[(size_t)n * 64 + lane] = fmaxf(num / fmaxf(den, 1e-16f) + b_r, 0.f);
  }
}

// ------------------------------------------------- GAT layer2: half-wave per node
// Blocked (4 consecutive node-pairs/wave) + 2-wide edge unroll per half.
__global__ __launch_bounds__(256) void gat2_k(
    const int* __restrict__ rowptr, const int* __restrict__ csr_src,
    const uint4* __restrict__ ea_h, const float* __restrict__ we,
    const float* __restrict__ att, const float* __restrict__ b,
    const float* __restrict__ xl, const float* __restrict__ xr,
    float* __restrict__ h, int N) {
  int t = threadIdx.x;
  int lane = t & 63;
  int c = lane & 31;
  int half = lane >> 5;
  int hbase = lane & 32;
  h2v wh[8];
#pragma unroll
  for (int k = 0; k < 8; ++k) {
    wh[k].x = (_Float16)we[(2 * k) * 32 + c];
    wh[k].y = (_Float16)we[(2 * k + 1) * 32 + c];
  }
  float att_r = att[c];
  float b_r = b[c];
  int wid = (blockIdx.x * blockDim.x + t) >> 6;
  int p0 = wid * 4;
  for (int jj = 0; jj < 4; ++jj) {
    int p = p0 + jj;
    if (p * 2 >= N) break;
    int n = p * 2 + half;
    if (n >= N) continue;
    float xr_v = xr[(size_t)n * 32 + c];
    float xl_s = xl[(size_t)n * 32 + c];
    float num = 0.f, den = 0.f, efsum = 0.f;
    int rs = rowptr[n], re = rowptr[n + 1];
    for (int base = rs; base < re; base += 32) {
      int cnt = min(32, re - base);
      int s_l = 0;
      if (c < cnt) s_l = csr_src[base + c];
      for (int i = 0; i < cnt; i += 2) {
        int j1 = min(i + 1, cnt - 1);
        int sa = __shfl(s_l, hbase + i), sb = __shfl(s_l, hbase + j1);
        float xa = xl[(size_t)sa * 32 + c];
        float xb = xl[(size_t)sb * 32 + c];
        const uint4* epa = ea_h + (size_t)(base + i) * 2;
        const uint4* epb = ea_h + (size_t)(base + j1) * 2;
        union { uint4 u; h2v h[4]; } a0, a1, c0, c1;
        a0.u = epa[0]; a1.u = epa[1];
        c0.u = epb[0]; c1.u = epb[1];
        float fa0 = 0.f, fa1 = 0.f, fb0 = 0.f, fb1 = 0.f;
        fa0 = __builtin_amdgcn_fdot2(a0.h[0], wh[0], fa0, false);
        fb0 = __builtin_amdgcn_fdot2(c0.h[0], wh[0], fb0, false);
        fa1 = __builtin_amdgcn_fdot2(a0.h[1], wh[1], fa1, false);
        fb1 = __builtin_amdgcn_fdot2(c0.h[1], wh[1], fb1, false);
        fa0 = __builtin_amdgcn_fdot2(a0.h[2], wh[2], fa0, false);
        fb0 = __builtin_amdgcn_fdot2(c0.h[2], wh[2], fb0, false);
        fa1 = __builtin_amdgcn_fdot2(a0.h[3], wh[3], fa1, false);
        fb1 = __builtin_amdgcn_fdot2(c0.h[3], wh[3], fb1, false);
        fa0 = __builtin_amdgcn_fdot2(a1.h[0], wh[4], fa0, false);
        fb0 = __builtin_amdgcn_fdot2(c1.h[0], wh[4], fb0, false);
        fa1 = __builtin_amdgcn_fdot2(a1.h[1], wh[5], fa1, false);
        fb1 = __builtin_amdgcn_fdot2(c1.h[1], wh[5], fb1, false);
        fa0 = __builtin_amdgcn_fdot2(a1.h[2], wh[6], fa0, false);
        fb0 = __builtin_amdgcn_fdot2(c1.h[2], wh[6], fb0, false);
        fa1 = __builtin_amdgcn_fdot2(a1.h[3], wh[7], fa1, false);
        fb1 = __builtin_amdgcn_fdot2(c1.h[3], wh[7], fb1, false);
        float fa = fa0 + fa1, fb = fb0 + fb1;
        float ma = xa + xr_v + fa; ma = (ma > 0.f) ? ma : NEG_SLOPE * ma;
        float mb = xb + xr_v + fb; mb = (mb > 0.f) ? mb : NEG_SLOPE * mb;
        float ta = ma * att_r, tb = mb * att_r;
#pragma unroll
        for (int off = 1; off < 32; off <<= 1) {
          ta += __shfl_xor(ta, off);
          tb += __shfl_xor(tb, off);
        }
        float ga = __expf(ta), gb = __expf(tb);
        float kb = (i + 1 < cnt) ? 1.f : 0.f;
        num += ga * xa + kb * gb * xb;
        den += ga + kb * gb;
        efsum += fa + kb * fb;
      }
    }
    int deg = re - rs;
    float ef_self = efsum / fmaxf((float)deg, 1.f);
    float mm = xl_s + xr_v + ef_self;
    mm = (mm > 0.f) ? mm : NEG_SLOPE * mm;
    float s2 = mm * att_r;
#pragma unroll
    for (int off = 1; off < 32; off <<= 1) s2 += __shfl_xor(s2, off);
    float e2 = __expf(s2);
    num += e2 * xl_s;
    den += e2;
    h[(size_t)n * 32 + c] = fmaxf(num / fmaxf(den, 1e-16f) + b_r, 0.f);
  }
}

// ------------------------------------------------- fused mean-pool + fc
__global__ __launch_bounds__(256) void pool_fc_k(
    const float* __restrict__ h, const int* __restrict__ batch,
    const float* __restrict__ wfc, const float* __restrict__ bfc,
    float* __restrict__ out, int N) {
  int g = blockIdx.x;
  __shared__ int srange[2];
  __shared__ float part[8][32];
  int t = threadIdx.x;
  if (t < 2) {
    int key = g + t;
    int lo = 0, hi = N;
    while (lo < hi) { int mid = (lo + hi) >> 1; if (batch[mid] < key) lo = mid + 1; else hi = mid; }
    srange[t] = lo;
  }
  __syncthreads();
  int rs = srange[0], re = srange[1];
  int c = t & 31, sub = t >> 5;
  float acc = 0.f;
  for (int n = rs + sub; n < re; n += 8) acc += h[(size_t)n * 32 + c];
  part[sub][c] = acc;
  __syncthreads();
  if (sub == 0) {
    float s = part[0][c];
#pragma unroll
    for (int i = 1; i < 8; ++i) s += part[i][c];
    part[0][c] = s / fmaxf((float)(re - rs), 1.f);
  }
  __syncthreads();
  if (sub == 0) {
    float a = 0.f;
#pragma unroll
    for (int k = 0; k < 32; ++k) a += part[0][k] * wfc[k * 32 + c];
    out[g * 32 + c] = a + bfc[c];
  }
}

// ----------------------------------------------------------------- launcher
extern "C" void kernel_launch(void* const* d_in, const int* in_sizes, int n_in,
                              void* d_out, int out_size, void* d_ws, size_t ws_size,
                              hipStream_t stream) {
  const float* x   = (const float*)d_in[0];
  const int*   ei  = (const int*)d_in[1];
  const float* ea  = (const float*)d_in[2];
  const int*   bat = (const int*)d_in[3];
  const float* wl1 = (const float*)d_in[4];
  const float* wr1 = (const float*)d_in[5];
  const float* we1 = (const float*)d_in[6];
  const float* at1 = (const float*)d_in[7];
  const float* b1  = (const float*)d_in[8];
  const float* wl2 = (const float*)d_in[9];
  const float* wr2 = (const float*)d_in[10];
  const float* we2 = (const float*)d_in[11];
  const float* at2 = (const float*)d_in[12];
  const float* b2  = (const float*)d_in[13];
  const float* wfc = (const float*)d_in[14];
  const float* bfc = (const float*)d_in[15];

  const int N = in_sizes[0] / 128;
  const int E = in_sizes[1] / 2;
  const int G = 256;
  const int* srcA = ei;
  const int* dstA = ei + E;

  // ---- workspace layout (~110 MB) ----
  uint4* ea_h   = (uint4*)d_ws;                      // E*2 uint4 (fp16 attrs)
  float* xl1    = (float*)(ea_h + (size_t)E * 2);    // N*64
  float* xr1    = xl1 + (size_t)N * 64;              // N*64
  int*   deg    = (int*)(xr1 + (size_t)N * 64);      // N
  int*   rowptr = deg + N;                           // N+1
  int*   cursor = rowptr + (N + 1);                  // N
  int*   aux    = cursor + N;                        // 512
  int*   csr_src= aux + 512;                         // E
  float* h1     = xr1;                               // in-place over xr1
  float* xl2    = xl1;                               // N*32
  float* xr2    = xl1 + (size_t)N * 32;              // N*32
  float* h2     = xr2;                               // in-place over xr2

  const int naux = (N + 255) / 256;

  // ---- CSR build + ea permute ----
  hipMemsetAsync(deg, 0, (size_t)N * sizeof(int), stream);
  deg_count_k<<<(E + 255) / 256, 256, 0, stream>>>(dstA, deg, E);
  scan1_k<<<naux, 256, 0, stream>>>(deg, rowptr, aux, N);
  scan2_k<<<1, 512, 0, stream>>>(aux, naux);
  scan3_k<<<(N + 256) / 256, 256, 0, stream>>>(rowptr, cursor, aux, N, E);
  scatter_k<<<(E + 255) / 256, 256, 0, stream>>>(srcA, dstA, ea, cursor, csr_src, ea_h, E);

  // ---- layer 1 ----
  transform1_k<<<2048, 256, 0, stream>>>(x, wl1, wr1, xl1, xr1, N);
  {
    int blocks1 = (N + 15) / 16;               // 4 waves/block * 4 nodes/wave
    gat1_k<<<blocks1, 256, 0, stream>>>(rowptr, csr_src, ea_h, we1, at1, b1,
                                        xl1, xr1, h1, N);
  }

  // ---- layer 2 ----
  transform2_k<<<1024, 256, 0, stream>>>(h1, wl2, wr2, xl2, xr2, N);
  {
    int P = (N + 1) / 2;
    int blocks2 = (P + 15) / 16;               // 4 waves/block * 4 pairs/wave
    gat2_k<<<blocks2, 256, 0, stream>>>(rowptr, csr_src, ea_h, we2, at2, b2,
                                        xl2, xr2, h2, N);
  }

  // ---- fused pool + fc ----
  pool_fc_k<<<G, 256, 0, stream>>>(h2, bat, wfc, bfc, (float*)d_out, N);
}

// Round 12
// 530.023 us; speedup vs baseline: 1.3852x; 1.0057x over previous
//
#include <hip/hip_runtime.h>
#include <hip/hip_bf16.h>
#include <hip/hip_fp16.h>

#define NEG_SLOPE 0.2f
#define LOG2E 1.4426950408889634f

typedef _Float16 h2v __attribute__((ext_vector_type(2)));

// ------------------------------------------------------------ CSR build
__global__ void deg_count_k(const int* __restrict__ dstA, int* __restrict__ deg, int E) {
  int e = blockIdx.x * blockDim.x + threadIdx.x;
  if (e < E) atomicAdd(&deg[dstA[e]], 1);
}

// exclusive scan, 3 phases (N <= 512*256)
__global__ void scan1_k(const int* __restrict__ deg, int* __restrict__ rowptr,
                        int* __restrict__ aux, int N) {
  __shared__ int sh[256];
  int t = threadIdx.x, i = blockIdx.x * 256 + t;
  int v = (i < N) ? deg[i] : 0;
  sh[t] = v; __syncthreads();
  for (int off = 1; off < 256; off <<= 1) {
    int x = (t >= off) ? sh[t - off] : 0;
    __syncthreads();
    sh[t] += x;
    __syncthreads();
  }
  if (i < N) rowptr[i] = sh[t] - v;
  if (t == 255) aux[blockIdx.x] = sh[255];
}

__global__ void scan2_k(int* __restrict__ aux, int naux) {
  __shared__ int sh[512];
  int t = threadIdx.x;
  int v = (t < naux) ? aux[t] : 0;
  sh[t] = v; __syncthreads();
  for (int off = 1; off < 512; off <<= 1) {
    int x = (t >= off) ? sh[t - off] : 0;
    __syncthreads();
    sh[t] += x;
    __syncthreads();
  }
  if (t < naux) aux[t] = sh[t] - v;
}

__global__ void scan3_k(int* __restrict__ rowptr, int* __restrict__ cursor,
                        const int* __restrict__ aux, int N, int E) {
  int i = blockIdx.x * blockDim.x + threadIdx.x;
  if (i < N) {
    int r = rowptr[i] + aux[i >> 8];
    rowptr[i] = r;
    cursor[i] = r;
  } else if (i == N) {
    rowptr[N] = E;
  }
}

// scatter: builds csr_src AND permuted fp16 edge-attrs (CSR order, 32B/edge)
__global__ void scatter_k(const int* __restrict__ srcA, const int* __restrict__ dstA,
                          const float* __restrict__ ea, int* __restrict__ cursor,
                          int* __restrict__ csr_src, uint4* __restrict__ ea_h, int E) {
  int e = blockIdx.x * blockDim.x + threadIdx.x;
  if (e >= E) return;
  int pos = atomicAdd(&cursor[dstA[e]], 1);
  csr_src[pos] = srcA[e];
  const float* p = ea + (size_t)e * 16;
  union { __half2 h2[8]; uint4 u[2]; } cv;
#pragma unroll
  for (int k = 0; k < 8; ++k) cv.h2[k] = __floats2half2_rn(p[2 * k], p[2 * k + 1]);
  uint4* d = ea_h + (size_t)pos * 2;
  d[0] = cv.u[0];
  d[1] = cv.u[1];
}

// ------------------------------------------------- layer1 node transform (128 -> 64|64)
__global__ __launch_bounds__(256) void transform1_k(
    const float* __restrict__ x, const float* __restrict__ wl, const float* __restrict__ wr,
    float* __restrict__ xl, float* __restrict__ xr, int N) {
  __shared__ float wS[128 * 128];
  __shared__ float xs[32 * 128];
  int t = threadIdx.x;
  for (int i = t; i < 128 * 64; i += 256) {
    int k = i >> 6, j = i & 63;
    wS[k * 128 + j]      = wl[i];
    wS[k * 128 + 64 + j] = wr[i];
  }
  __syncthreads();
  int tc = t & 31;
  int tr = t >> 5;
  int ntiles = (N + 31) >> 5;
  for (int tile = blockIdx.x; tile < ntiles; tile += gridDim.x) {
    int base = tile << 5;
    const float4* x4 = (const float4*)x;
    float4* xs4 = (float4*)xs;
    for (int i = t; i < 1024; i += 256) {
      int node = base + (i >> 5);
      float4 v = {0.f, 0.f, 0.f, 0.f};
      if (node < N) v = x4[(size_t)node * 32 + (i & 31)];
      xs4[i] = v;
    }
    __syncthreads();
    float4 acc0 = {0,0,0,0}, acc1 = {0,0,0,0}, acc2 = {0,0,0,0}, acc3 = {0,0,0,0};
    const float* xrow = &xs[tr * 4 * 128];
#pragma unroll 4
    for (int k = 0; k < 128; ++k) {
      float4 w4 = *(const float4*)&wS[k * 128 + tc * 4];
      float x0 = xrow[k], x1 = xrow[128 + k], x2 = xrow[256 + k], x3 = xrow[384 + k];
      acc0.x += x0 * w4.x; acc0.y += x0 * w4.y; acc0.z += x0 * w4.z; acc0.w += x0 * w4.w;
      acc1.x += x1 * w4.x; acc1.y += x1 * w4.y; acc1.z += x1 * w4.z; acc1.w += x1 * w4.w;
      acc2.x += x2 * w4.x; acc2.y += x2 * w4.y; acc2.z += x2 * w4.z; acc2.w += x2 * w4.w;
      acc3.x += x3 * w4.x; acc3.y += x3 * w4.y; acc3.z += x3 * w4.z; acc3.w += x3 * w4.w;
    }
    float* dp = (tc < 16) ? xl : xr;
    int j4 = (tc & 15) * 4;
    int nb = base + tr * 4;
    if (nb + 0 < N) *(float4*)&dp[(size_t)(nb + 0) * 64 + j4] = acc0;
    if (nb + 1 < N) *(float4*)&dp[(size_t)(nb + 1) * 64 + j4] = acc1;
    if (nb + 2 < N) *(float4*)&dp[(size_t)(nb + 2) * 64 + j4] = acc2;
    if (nb + 3 < N) *(float4*)&dp[(size_t)(nb + 3) * 64 + j4] = acc3;
    __syncthreads();
  }
}

// ------------------------------------------------- layer2 node transform (64 -> 32|32)
__global__ __launch_bounds__(256) void transform2_k(
    const float* __restrict__ h, const float* __restrict__ wl, const float* __restrict__ wr,
    float* __restrict__ xl, float* __restrict__ xr, int N) {
  __shared__ float wS[64 * 64];
  __shared__ float xs[64 * 64];
  int t = threadIdx.x;
  for (int i = t; i < 64 * 32; i += 256) {
    int k = i >> 5, j = i & 31;
    wS[k * 64 + j]      = wl[i];
    wS[k * 64 + 32 + j] = wr[i];
  }
  __syncthreads();
  int tc = t & 15;
  int tr = t >> 4;
  int ntiles = (N + 63) >> 6;
  for (int tile = blockIdx.x; tile < ntiles; tile += gridDim.x) {
    int base = tile << 6;
    const float4* h4 = (const float4*)h;
    float4* xs4 = (float4*)xs;
    for (int i = t; i < 1024; i += 256) {
      int node = base + (i >> 4);
      float4 v = {0.f, 0.f, 0.f, 0.f};
      if (node < N) v = h4[(size_t)node * 16 + (i & 15)];
      xs4[i] = v;
    }
    __syncthreads();
    float4 acc0 = {0,0,0,0}, acc1 = {0,0,0,0}, acc2 = {0,0,0,0}, acc3 = {0,0,0,0};
    const float* xrow = &xs[tr * 4 * 64];
#pragma unroll 4
    for (int k = 0; k < 64; ++k) {
      float4 w4 = *(const float4*)&wS[k * 64 + tc * 4];
      float x0 = xrow[k], x1 = xrow[64 + k], x2 = xrow[128 + k], x3 = xrow[192 + k];
      acc0.x += x0 * w4.x; acc0.y += x0 * w4.y; acc0.z += x0 * w4.z; acc0.w += x0 * w4.w;
      acc1.x += x1 * w4.x; acc1.y += x1 * w4.y; acc1.z += x1 * w4.z; acc1.w += x1 * w4.w;
      acc2.x += x2 * w4.x; acc2.y += x2 * w4.y; acc2.z += x2 * w4.z; acc2.w += x2 * w4.w;
      acc3.x += x3 * w4.x; acc3.y += x3 * w4.y; acc3.z += x3 * w4.z; acc3.w += x3 * w4.w;
    }
    float* dp = (tc < 8) ? xl : xr;
    int j4 = (tc & 7) * 4;
    int nb = base + tr * 4;
    if (nb + 0 < N) *(float4*)&dp[(size_t)(nb + 0) * 32 + j4] = acc0;
    if (nb + 1 < N) *(float4*)&dp[(size_t)(nb + 1) * 32 + j4] = acc1;
    if (nb + 2 < N) *(float4*)&dp[(size_t)(nb + 2) * 32 + j4] = acc2;
    if (nb + 3 < N) *(float4*)&dp[(size_t)(nb + 3) * 32 + j4] = acc3;
    __syncthreads();
  }
}

// ------------------------------------------------- GAT layer1: one wave per node (pull)
// Mask-free 2-wide main loop + single-edge tail; att pre-scaled by log2e -> exp2f.
__global__ __launch_bounds__(256) void gat1_k(
    const int* __restrict__ rowptr, const int* __restrict__ csr_src,
    const uint4* __restrict__ ea_h, const float* __restrict__ we,
    const float* __restrict__ att, const float* __restrict__ b,
    const float* __restrict__ xl, const float* __restrict__ xr,
    float* __restrict__ h, int N) {
  int t = threadIdx.x;
  int lane = t & 63;
  h2v wh[8];
#pragma unroll
  for (int k = 0; k < 8; ++k) {
    wh[k].x = (_Float16)we[(2 * k) * 64 + lane];
    wh[k].y = (_Float16)we[(2 * k + 1) * 64 + lane];
  }
  float att_r = att[lane] * LOG2E;
  float b_r = b[lane];
  int wid = (blockIdx.x * blockDim.x + t) >> 6;
  int n0 = wid * 4;
  for (int jj = 0; jj < 4; ++jj) {
    int n = n0 + jj;
    if (n >= N) break;
    float xr_v = xr[(size_t)n * 64 + lane];
    float xl_s = xl[(size_t)n * 64 + lane];
    float num = 0.f, den = 0.f, efsum = 0.f;
    int rs = __builtin_amdgcn_readfirstlane(rowptr[n]);
    int re = __builtin_amdgcn_readfirstlane(rowptr[n + 1]);
    for (int base = rs; base < re; base += 64) {
      int cnt = min(64, re - base);
      int s_l = 0;
      if (lane < cnt) s_l = csr_src[base + lane];
      int i = 0;
      for (; i + 1 < cnt; i += 2) {
        int sa = __shfl(s_l, i), sb = __shfl(s_l, i + 1);
        float xa = xl[(size_t)sa * 64 + lane];
        float xb = xl[(size_t)sb * 64 + lane];
        const uint4* epa = ea_h + (size_t)(base + i) * 2;
        union { uint4 u; h2v h[4]; } a0, a1, c0, c1;
        a0.u = epa[0]; a1.u = epa[1];
        c0.u = epa[2]; c1.u = epa[3];        // edge i+1 contiguous
        float fa0 = 0.f, fa1 = 0.f, fb0 = 0.f, fb1 = 0.f;
        fa0 = __builtin_amdgcn_fdot2(a0.h[0], wh[0], fa0, false);
        fb0 = __builtin_amdgcn_fdot2(c0.h[0], wh[0], fb0, false);
        fa1 = __builtin_amdgcn_fdot2(a0.h[1], wh[1], fa1, false);
        fb1 = __builtin_amdgcn_fdot2(c0.h[1], wh[1], fb1, false);
        fa0 = __builtin_amdgcn_fdot2(a0.h[2], wh[2], fa0, false);
        fb0 = __builtin_amdgcn_fdot2(c0.h[2], wh[2], fb0, false);
        fa1 = __builtin_amdgcn_fdot2(a0.h[3], wh[3], fa1, false);
        fb1 = __builtin_amdgcn_fdot2(c0.h[3], wh[3], fb1, false);
        fa0 = __builtin_amdgcn_fdot2(a1.h[0], wh[4], fa0, false);
        fb0 = __builtin_amdgcn_fdot2(c1.h[0], wh[4], fb0, false);
        fa1 = __builtin_amdgcn_fdot2(a1.h[1], wh[5], fa1, false);
        fb1 = __builtin_amdgcn_fdot2(c1.h[1], wh[5], fb1, false);
        fa0 = __builtin_amdgcn_fdot2(a1.h[2], wh[6], fa0, false);
        fb0 = __builtin_amdgcn_fdot2(c1.h[2], wh[6], fb0, false);
        fa1 = __builtin_amdgcn_fdot2(a1.h[3], wh[7], fa1, false);
        fb1 = __builtin_amdgcn_fdot2(c1.h[3], wh[7], fb1, false);
        float fa = fa0 + fa1, fb = fb0 + fb1;
        float ma = xa + xr_v + fa; ma = (ma > 0.f) ? ma : NEG_SLOPE * ma;
        float mb = xb + xr_v + fb; mb = (mb > 0.f) ? mb : NEG_SLOPE * mb;
        float ta = ma * att_r, tb = mb * att_r;
#pragma unroll
        for (int off = 1; off < 32; off <<= 1) {
          ta += __shfl_xor(ta, off);
          tb += __shfl_xor(tb, off);
        }
        float ga = exp2f(ta), gb = exp2f(tb);
        num += ga * xa + gb * xb;
        den += ga + gb;
        efsum += fa + fb;
      }
      if (i < cnt) {                          // single tail edge, unmasked
        int sa = __shfl(s_l, i);
        float xa = xl[(size_t)sa * 64 + lane];
        const uint4* epa = ea_h + (size_t)(base + i) * 2;
        union { uint4 u; h2v h[4]; } a0, a1;
        a0.u = epa[0]; a1.u = epa[1];
        float fa0 = 0.f, fa1 = 0.f;
        fa0 = __builtin_amdgcn_fdot2(a0.h[0], wh[0], fa0, false);
        fa1 = __builtin_amdgcn_fdot2(a0.h[1], wh[1], fa1, false);
        fa0 = __builtin_amdgcn_fdot2(a0.h[2], wh[2], fa0, false);
        fa1 = __builtin_amdgcn_fdot2(a0.h[3], wh[3], fa1, false);
        fa0 = __builtin_amdgcn_fdot2(a1.h[0], wh[4], fa0, false);
        fa1 = __builtin_amdgcn_fdot2(a1.h[1], wh[5], fa1, false);
        fa0 = __builtin_amdgcn_fdot2(a1.h[2], wh[6], fa0, false);
        fa1 = __builtin_amdgcn_fdot2(a1.h[3], wh[7], fa1, false);
        float fa = fa0 + fa1;
        float ma = xa + xr_v + fa; ma = (ma > 0.f) ? ma : NEG_SLOPE * ma;
        float ta = ma * att_r;
#pragma unroll
        for (int off = 1; off < 32; off <<= 1) ta += __shfl_xor(ta, off);
        float ga = exp2f(ta);
        num += ga * xa;
        den += ga;
        efsum += fa;
      }
    }
    // self loop: ef_self = mean(ea@we) = efsum/deg
    int deg = re - rs;
    float ef_self = efsum / fmaxf((float)deg, 1.f);
    float mm = xl_s + xr_v + ef_self;
    mm = (mm > 0.f) ? mm : NEG_SLOPE * mm;
    float s2 = mm * att_r;
#pragma unroll
    for (int off = 1; off < 32; off <<= 1) s2 += __shfl_xor(s2, off);
    float e2 = exp2f(s2);
    num += e2 * xl_s;
    den += e2;
    h[(size_t)n * 64 + lane] = fmaxf(num / fmaxf(den, 1e-16f) + b_r, 0.f);
  }
}

// ------------------------------------------------- GAT layer2: half-wave per node
__global__ __launch_bounds__(256) void gat2_k(
    const int* __restrict__ rowptr, const int* __restrict__ csr_src,
    const uint4* __restrict__ ea_h, const float* __restrict__ we,
    const float* __restrict__ att, const float* __restrict__ b,
    const float* __restrict__ xl, const float* __restrict__ xr,
    float* __restrict__ h, int N) {
  int t = threadIdx.x;
  int lane = t & 63;
  int c = lane & 31;
  int half = lane >> 5;
  int hbase = lane & 32;
  h2v wh[8];
#pragma unroll
  for (int k = 0; k < 8; ++k) {
    wh[k].x = (_Float16)we[(2 * k) * 32 + c];
    wh[k].y = (_Float16)we[(2 * k + 1) * 32 + c];
  }
  float att_r = att[c] * LOG2E;
  float b_r = b[c];
  int wid = (blockIdx.x * blockDim.x + t) >> 6;
  int p0 = wid * 4;
  for (int jj = 0; jj < 4; ++jj) {
    int p = p0 + jj;
    if (p * 2 >= N) break;
    int n = p * 2 + half;
    if (n >= N) continue;
    float xr_v = xr[(size_t)n * 32 + c];
    float xl_s = xl[(size_t)n * 32 + c];
    float num = 0.f, den = 0.f, efsum = 0.f;
    int rs = rowptr[n], re = rowptr[n + 1];
    for (int base = rs; base < re; base += 32) {
      int cnt = min(32, re - base);
      int s_l = 0;
      if (c < cnt) s_l = csr_src[base + c];
      int i = 0;
      for (; i + 1 < cnt; i += 2) {
        int sa = __shfl(s_l, hbase + i), sb = __shfl(s_l, hbase + i + 1);
        float xa = xl[(size_t)sa * 32 + c];
        float xb = xl[(size_t)sb * 32 + c];
        const uint4* epa = ea_h + (size_t)(base + i) * 2;
        union { uint4 u; h2v h[4]; } a0, a1, c0, c1;
        a0.u = epa[0]; a1.u = epa[1];
        c0.u = epa[2]; c1.u = epa[3];
        float fa0 = 0.f, fa1 = 0.f, fb0 = 0.f, fb1 = 0.f;
        fa0 = __builtin_amdgcn_fdot2(a0.h[0], wh[0], fa0, false);
        fb0 = __builtin_amdgcn_fdot2(c0.h[0], wh[0], fb0, false);
        fa1 = __builtin_amdgcn_fdot2(a0.h[1], wh[1], fa1, false);
        fb1 = __builtin_amdgcn_fdot2(c0.h[1], wh[1], fb1, false);
        fa0 = __builtin_amdgcn_fdot2(a0.h[2], wh[2], fa0, false);
        fb0 = __builtin_amdgcn_fdot2(c0.h[2], wh[2], fb0, false);
        fa1 = __builtin_amdgcn_fdot2(a0.h[3], wh[3], fa1, false);
        fb1 = __builtin_amdgcn_fdot2(c0.h[3], wh[3], fb1, false);
        fa0 = __builtin_amdgcn_fdot2(a1.h[0], wh[4], fa0, false);
        fb0 = __builtin_amdgcn_fdot2(c1.h[0], wh[4], fb0, false);
        fa1 = __builtin_amdgcn_fdot2(a1.h[1], wh[5], fa1, false);
        fb1 = __builtin_amdgcn_fdot2(c1.h[1], wh[5], fb1, false);
        fa0 = __builtin_amdgcn_fdot2(a1.h[2], wh[6], fa0, false);
        fb0 = __builtin_amdgcn_fdot2(c1.h[2], wh[6], fb0, false);
        fa1 = __builtin_amdgcn_fdot2(a1.h[3], wh[7], fa1, false);
        fb1 = __builtin_amdgcn_fdot2(c1.h[3], wh[7], fb1, false);
        float fa = fa0 + fa1, fb = fb0 + fb1;
        float ma = xa + xr_v + fa; ma = (ma > 0.f) ? ma : NEG_SLOPE * ma;
        float mb = xb + xr_v + fb; mb = (mb > 0.f) ? mb : NEG_SLOPE * mb;
        float ta = ma * att_r, tb = mb * att_r;
#pragma unroll
        for (int off = 1; off < 32; off <<= 1) {
          ta += __shfl_xor(ta, off);
          tb += __shfl_xor(tb, off);
        }
        float ga = exp2f(ta), gb = exp2f(tb);
        num += ga * xa + gb * xb;
        den += ga + gb;
        efsum += fa + fb;
      }
      if (i < cnt) {
        int sa = __shfl(s_l, hbase + i);
        float xa = xl[(size_t)sa * 32 + c];
        const uint4* epa = ea_h + (size_t)(base + i) * 2;
        union { uint4 u; h2v h[4]; } a0, a1;
        a0.u = epa[0]; a1.u = epa[1];
        float fa0 = 0.f, fa1 = 0.f;
        fa0 = __builtin_amdgcn_fdot2(a0.h[0], wh[0], fa0, false);
        fa1 = __builtin_amdgcn_fdot2(a0.h[1], wh[1], fa1, false);
        fa0 = __builtin_amdgcn_fdot2(a0.h[2], wh[2], fa0, false);
        fa1 = __builtin_amdgcn_fdot2(a0.h[3], wh[3], fa1, false);
        fa0 = __builtin_amdgcn_fdot2(a1.h[0], wh[4], fa0, false);
        fa1 = __builtin_amdgcn_fdot2(a1.h[1], wh[5], fa1, false);
        fa0 = __builtin_amdgcn_fdot2(a1.h[2], wh[6], fa0, false);
        fa1 = __builtin_amdgcn_fdot2(a1.h[3], wh[7], fa1, false);
        float fa = fa0 + fa1;
        float ma = xa + xr_v + fa; ma = (ma > 0.f) ? ma : NEG_SLOPE * ma;
        float ta = ma * att_r;
#pragma unroll
        for (int off = 1; off < 32; off <<= 1) ta += __shfl_xor(ta, off);
        float ga = exp2f(ta);
        num += ga * xa;
        den += ga;
        efsum += fa;
      }
    }
    int deg = re - rs;
    float ef_self = efsum / fmaxf((float)deg, 1.f);
    float mm = xl_s + xr_v + ef_self;
    mm = (mm > 0.f) ? mm : NEG_SLOPE * mm;
    float s2 = mm * att_r;
#pragma unroll
    for (int off = 1; off < 32; off <<= 1) s2 += __shfl_xor(s2, off);
    float e2 = exp2f(s2);
    num += e2 * xl_s;
    den += e2;
    h[(size_t)n * 32 + c] = fmaxf(num / fmaxf(den, 1e-16f) + b_r, 0.f);
  }
}

// ------------------------------------------------- fused mean-pool + fc
__global__ __launch_bounds__(256) void pool_fc_k(
    const float* __restrict__ h, const int* __restrict__ batch,
    const float* __restrict__ wfc, const float* __restrict__ bfc,
    float* __restrict__ out, int N) {
  int g = blockIdx.x;
  __shared__ int srange[2];
  __shared__ float part[8][32];
  int t = threadIdx.x;
  if (t < 2) {
    int key = g + t;
    int lo = 0, hi = N;
    while (lo < hi) { int mid = (lo + hi) >> 1; if (batch[mid] < key) lo = mid + 1; else hi = mid; }
    srange[t] = lo;
  }
  __syncthreads();
  int rs = srange[0], re = srange[1];
  int c = t & 31, sub = t >> 5;
  float acc = 0.f;
  for (int n = rs + sub; n < re; n += 8) acc += h[(size_t)n * 32 + c];
  part[sub][c] = acc;
  __syncthreads();
  if (sub == 0) {
    float s = part[0][c];
#pragma unroll
    for (int i = 1; i < 8; ++i) s += part[i][c];
    part[0][c] = s / fmaxf((float)(re - rs), 1.f);
  }
  __syncthreads();
  if (sub == 0) {
    float a = 0.f;
#pragma unroll
    for (int k = 0; k < 32; ++k) a += part[0][k] * wfc[k * 32 + c];
    out[g * 32 + c] = a + bfc[c];
  }
}

// ----------------------------------------------------------------- launcher
extern "C" void kernel_launch(void* const* d_in, const int* in_sizes, int n_in,
                              void* d_out, int out_size, void* d_ws, size_t ws_size,
                              hipStream_t stream) {
  const float* x   = (const float*)d_in[0];
  const int*   ei  = (const int*)d_in[1];
  const float* ea  = (const float*)d_in[2];
  const int*   bat = (const int*)d_in[3];
  const float* wl1 = (const float*)d_in[4];
  const float* wr1 = (const float*)d_in[5];
  const float* we1 = (const float*)d_in[6];
  const float* at1 = (const float*)d_in[7];
  const float* b1  = (const float*)d_in[8];
  const float* wl2 = (const float*)d_in[9];
  const float* wr2 = (const float*)d_in[10];
  const float* we2 = (const float*)d_in[11];
  const float* at2 = (const float*)d_in[12];
  const float* b2  = (const float*)d_in[13];
  const float* wfc = (const float*)d_in[14];
  const float* bfc = (const float*)d_in[15];

  const int N = in_sizes[0] / 128;
  const int E = in_sizes[1] / 2;
  const int G = 256;
  const int* srcA = ei;
  const int* dstA = ei + E;

  // ---- workspace layout (~110 MB) ----
  uint4* ea_h   = (uint4*)d_ws;                      // E*2 uint4 (fp16 attrs)
  float* xl1    = (float*)(ea_h + (size_t)E * 2);    // N*64
  float* xr1    = xl1 + (size_t)N * 64;              // N*64
  int*   deg    = (int*)(xr1 + (size_t)N * 64);      // N
  int*   rowptr = deg + N;                           // N+1
  int*   cursor = rowptr + (N + 1);                  // N
  int*   aux    = cursor + N;                        // 512
  int*   csr_src= aux + 512;                         // E
  float* h1     = xr1;                               // in-place over xr1
  float* xl2    = xl1;                               // N*32
  float* xr2    = xl1 + (size_t)N * 32;              // N*32
  float* h2     = xr2;                               // in-place over xr2

  const int naux = (N + 255) / 256;

  // ---- CSR build + ea permute ----
  hipMemsetAsync(deg, 0, (size_t)N * sizeof(int), stream);
  deg_count_k<<<(E + 255) / 256, 256, 0, stream>>>(dstA, deg, E);
  scan1_k<<<naux, 256, 0, stream>>>(deg, rowptr, aux, N);
  scan2_k<<<1, 512, 0, stream>>>(aux, naux);
  scan3_k<<<(N + 256) / 256, 256, 0, stream>>>(rowptr, cursor, aux, N, E);
  scatter_k<<<(E + 255) / 256, 256, 0, stream>>>(srcA, dstA, ea, cursor, csr_src, ea_h, E);

  // ---- layer 1 ----
  transform1_k<<<(N + 31) / 32, 256, 0, stream>>>(x, wl1, wr1, xl1, xr1, N);
  {
    int blocks1 = (N + 15) / 16;               // 4 waves/block * 4 nodes/wave
    gat1_k<<<blocks1, 256, 0, stream>>>(rowptr, csr_src, ea_h, we1, at1, b1,
                                        xl1, xr1, h1, N);
  }

  // ---- layer 2 ----
  transform2_k<<<(N + 63) / 64, 256, 0, stream>>>(h1, wl2, wr2, xl2, xr2, N);
  {
    int P = (N + 1) / 2;
    int blocks2 = (P + 15) / 16;               // 4 waves/block * 4 pairs/wave
    gat2_k<<<blocks2, 256, 0, stream>>>(rowptr, csr_src, ea_h, we2, at2, b2,
                                        xl2, xr2, h2, N);
  }

  // ---- fused pool + fc ----
  pool_fc_k<<<G, 256, 0, stream>>>(h2, bat, wfc, bfc, (float*)d_out, N);
}